// Round 4
// baseline (864.225 us; speedup 1.0000x reference)
//
#include <hip/hip_runtime.h>

// ============================================================================
// Attention_18923625906467 — MI355X (round 11)
//   out = ((x@Wsep^T)@Wmulti^T -> heads -> softmax(QK^T/sqrt(512))V) @ Wres^T
// B=2,S=2048,D=512,H=8.  f32 in/out; bf16 MFMA compute (2%-rel threshold).
//
// R10: attn 300 µs (MfmaUtil 19%, conflicts 2.5e7 unchanged), GEMM2 ~300 µs.
// R11 fixes, no schedule change:
//  (1) attn V/P swizzle key was (row&3) -> 4-way phase conflicts on 64B rows;
//      correct key is ((row>>1)&3): each 8-lane phase hits 8 distinct 16B
//      slots (row parity supplies the 64B half, key the 16B slot).
//  (2) attn staging addresses hoisted to per-thread base pointers.
//  (3) gemm_bt qk-mode epilogue: C-tile repacked via LDS (transposed for the
//      vT region) then stored as bf16x8 -> kills the 4-16x sector
//      amplification of the scalar scatter (vT lanes were 2B @ 4KB stride).
// ============================================================================

typedef __bf16 bf16_t;
typedef __bf16 bf16x4 __attribute__((ext_vector_type(4)));
typedef __bf16 bf16x8 __attribute__((ext_vector_type(8)));
typedef float  f32x4  __attribute__((ext_vector_type(4)));

#define BM 128
#define BN 128
#define BK 64
#define LDK 72    // GEMM LDS row stride (bf16)
#define LDC 136   // epilogue repack row stride (bf16): mult of 8 for b128 reads

typedef const __attribute__((address_space(1))) void gvoid_t;
typedef __attribute__((address_space(3))) void svoid_t;

__device__ __forceinline__ void async_cp16(const bf16_t* g, bf16_t* l)
{
    __builtin_amdgcn_global_load_lds((gvoid_t*)g, (svoid_t*)l, 16, 0, 0);
}

__device__ __forceinline__ void bar_lgkm()
{
    asm volatile("s_waitcnt lgkmcnt(0)" ::: "memory");
    __builtin_amdgcn_s_barrier();
}

__device__ __forceinline__ void wait_vm0()
{
    asm volatile("s_waitcnt vmcnt(0)" ::: "memory");
}

// ---------------------------------------------------------------------------
__global__ void f32_to_bf16(const float* __restrict__ src, bf16_t* __restrict__ dst, int n4)
{
    const int i = blockIdx.x * 256 + threadIdx.x;
    if (i < n4) {
        const float4 v = ((const float4*)src)[i];
        bf16x4 o;
        o[0] = (bf16_t)v.x; o[1] = (bf16_t)v.y; o[2] = (bf16_t)v.z; o[3] = (bf16_t)v.w;
        ((bf16x4*)dst)[i] = o;
    }
}

// ---------------------------------------------------------------------------
// GEMM: D = A @ W^T + bias.  A:[M,lda], W:[N,ldw] row-major bf16, K inner.
//   C    != nullptr : write bf16 C[row*N+col]
//   Cacc != nullptr : f32 Cacc[row*N+col] = v (accFirst) or += v
//   qk   != nullptr : attention scatter; tiles are region-pure (1536%128==0,
//       split at col%1536==1024):
//       qk tiles: qk[((bb*hmul+hh)*2048+ss)*1024 + off]   row-major in ss
//       vT tiles: vT[((bb*hmul+hh)*512+d)*2048 + ss]      row-major in d
//       Both stored via LDS repack -> bf16x8 coalesced stores.
// ---------------------------------------------------------------------------
__global__ __launch_bounds__(256, 2)
void gemm_bt(const bf16_t* __restrict__ A, int lda,
             const bf16_t* __restrict__ W, int ldw,
             const float* __restrict__ bias,
             bf16_t* __restrict__ C, float* __restrict__ Cacc, int accFirst,
             int N, int K,
             bf16_t* __restrict__ qk, bf16_t* __restrict__ vT, int hmul)
{
    __shared__ __align__(16) bf16_t smem[BM * LDK + BN * LDK];   // 36 KB
    bf16_t* As = smem;
    bf16_t* Ws = smem + BM * LDK;

    const int tid  = threadIdx.x;
    const int wave = tid >> 6;
    const int lane = tid & 63;
    const int quad = lane >> 4;
    const int l16  = lane & 15;
    const int bm = blockIdx.y * BM;
    const int bn = blockIdx.x * BN;
    const int wm = (wave >> 1) * 64;
    const int wn = (wave & 1) * 64;

    f32x4 acc[4][4] = {};

    const int srow = tid >> 3;
    const int sseg = tid & 7;

    for (int k0 = 0; k0 < K; k0 += BK) {
        #pragma unroll
        for (int it = 0; it < 4; ++it) {
            const int row = it * 32 + srow;
            const int4 va = *(const int4*)(A + (size_t)(bm + row) * lda + k0 + sseg * 8);
            *(int4*)(As + row * LDK + sseg * 8) = va;
            const int4 vw = *(const int4*)(W + (size_t)(bn + row) * ldw + k0 + sseg * 8);
            *(int4*)(Ws + row * LDK + sseg * 8) = vw;
        }
        __syncthreads();
        #pragma unroll
        for (int kk = 0; kk < BK; kk += 32) {
            bf16x8 af[4], wf[4];
            #pragma unroll
            for (int i = 0; i < 4; ++i)
                af[i] = *(const bf16x8*)(As + (wm + i * 16 + l16) * LDK + kk + quad * 8);
            #pragma unroll
            for (int j = 0; j < 4; ++j)
                wf[j] = *(const bf16x8*)(Ws + (wn + j * 16 + l16) * LDK + kk + quad * 8);
            #pragma unroll
            for (int i = 0; i < 4; ++i)
                #pragma unroll
                for (int j = 0; j < 4; ++j)
                    acc[i][j] = __builtin_amdgcn_mfma_f32_16x16x32_bf16(af[i], wf[j], acc[i][j], 0, 0, 0);
        }
        __syncthreads();
    }

    if (qk) {
        // ---- attention scatter via LDS repack (As/Ws dead; 128x136 fits) ----
        bf16_t* Ct = smem;
        const int off0 = bn % 1536;       // uniform per block
        const int hh   = bn / 1536;
        const int isV  = (off0 >= 1024);
        #pragma unroll
        for (int j = 0; j < 4; ++j) {
            const int lc = wn + j * 16 + l16;
            const float bv = bias ? bias[bn + lc] : 0.f;
            #pragma unroll
            for (int i = 0; i < 4; ++i)
                #pragma unroll
                for (int r = 0; r < 4; ++r) {
                    const int lr = wm + i * 16 + quad * 4 + r;
                    const float v = acc[i][j][r] + bv;
                    if (isV) Ct[lc * LDC + lr] = (bf16_t)v;   // transposed
                    else     Ct[lr * LDC + lc] = (bf16_t)v;   // row-major
                }
        }
        __syncthreads();
        const int bb  = bm >> 11;
        const int ssb = bm & 2047;
        if (isV) {
            const int dbase = off0 - 1024;
            #pragma unroll
            for (int pass = 0; pass < 8; ++pass) {
                const int e   = pass * 256 + tid;
                const int lc  = e >> 4;           // d within tile
                const int lr0 = (e & 15) * 8;     // ss octet
                const bf16x8 vv = *(const bf16x8*)(Ct + lc * LDC + lr0);
                *(bf16x8*)(vT + ((size_t)((bb * hmul + hh) * 512 + dbase + lc)) * 2048
                               + ssb + lr0) = vv;
            }
        } else {
            #pragma unroll
            for (int pass = 0; pass < 8; ++pass) {
                const int e   = pass * 256 + tid;
                const int lr  = e >> 4;           // ss within tile
                const int lc0 = (e & 15) * 8;     // off octet
                const bf16x8 vv = *(const bf16x8*)(Ct + lr * LDC + lc0);
                *(bf16x8*)(qk + ((size_t)((bb * hmul + hh) * 2048 + ssb + lr)) * 1024
                               + off0 + lc0) = vv;
            }
        }
        return;
    }

    #pragma unroll
    for (int j = 0; j < 4; ++j) {
        const int col = bn + wn + j * 16 + l16;
        const float bv = bias ? bias[col] : 0.f;
        #pragma unroll
        for (int i = 0; i < 4; ++i) {
            const int row0 = bm + wm + i * 16 + quad * 4;
            #pragma unroll
            for (int r = 0; r < 4; ++r) {
                const int row = row0 + r;
                const float v = acc[i][j][r] + bv;
                if (C)
                    C[(size_t)row * N + col] = (bf16_t)v;
                if (Cacc) {
                    const size_t idx = (size_t)row * N + col;
                    Cacc[idx] = accFirst ? v : (Cacc[idx] + v);
                }
            }
        }
    }
}

// ---------------------------------------------------------------------------
// Flash attention, round-11 (R10 schedule + fixed swizzle keys).
// Grid nPairs*16 blocks x 512 thr (8 waves, 128 q-rows/block); 1 block/CU.
// KT=32 keys/step, 64 steps; K and V double-buffered in LDS.
// Per step t (buf b = t&1):
//   issue stage(t+1) -> buf b^1
//   QK from Ks[b]; softmax (defer-max); P+alpha -> LDS
//   B1: lgkmcnt(0)+s_barrier      [NO vmcnt drain]
//   rescale (guarded); PV from Vs[b]+Plds
//   vmcnt(0); Bend: lgkmcnt(0)+s_barrier
// Swizzle keys (64B rows: Vs/Plds): ((row>>1)&3) — each 8-lane read phase
// hits 8 distinct 16B slots (parity picks the 64B half, key the slot).
// Ks (1KB rows): key (l16&7) unchanged (conflict-free).
// ---------------------------------------------------------------------------
__global__ __launch_bounds__(512, 2)
void attn(const bf16_t* __restrict__ qk, const bf16_t* __restrict__ vT,
          bf16_t* __restrict__ aout, int nPairs, int nH,
          int out_stride, int coloff_per_head)
{
    __shared__ __align__(16) bf16_t Ks[2 * 32 * 512];   // 64 KB
    __shared__ __align__(16) bf16_t Vs[2 * 512 * 32];   // 64 KB
    __shared__ __align__(16) bf16_t Plds[128 * 32];     //  8 KB
    __shared__ float aLds[128];
    __shared__ float lLds[128];

    const int tid  = threadIdx.x;
    const int wave = tid >> 6;
    const int lane = tid & 63;
    const int quad = lane >> 4;
    const int l16  = lane & 15;
    const int qh   = wave >> 2;       // PV q-half  (0..1)
    const int dw   = wave & 3;        // PV d-block (0..3)

    const int bid = blockIdx.x;
    const int p   = bid % nPairs;     // pair (b*nH + h)
    const int qt  = bid / nPairs;     // 0..15

    const bf16_t* qp = qk + ((size_t)(p * 2048 + qt * 128 + wave * 16)) * 1024;
    const bf16_t* kp = qk + ((size_t)(p * 2048)) * 1024 + 512;
    const bf16_t* vp = vT + (size_t)p * 512 * 2048;

    // ---- per-thread staging base addresses (hoisted; step adds key0 only) --
    const bf16_t* ksrc[2]; const bf16_t* vsrc[2];
    int kdo[2], vdo[2];
    #pragma unroll
    for (int it = 0; it < 2; ++it) {
        {   // K: slot/64 = row(0..31), slot%64 = seg; LDS[r][s] = G[r][s^(r&7)]
            const int slot = it * 512 + tid;
            const int row  = slot >> 6;
            const int gseg = (slot & 63) ^ (row & 7);
            ksrc[it] = kp + (size_t)row * 1024 + gseg * 8;
            kdo[it]  = slot * 8;
        }
        {   // V: slot/4 = row(0..511), slot%4 = seg; LDS[r][s] = G[r][s^((r>>1)&3)]
            const int slot = it * 512 + tid;
            const int row  = slot >> 2;
            const int gseg = (slot & 3) ^ ((slot >> 3) & 3);
            vsrc[it] = vp + (size_t)row * 2048 + gseg * 8;
            vdo[it]  = slot * 8;
        }
    }
    #pragma unroll
    for (int it = 2; it < 4; ++it) { }   // (4 slots total handled below)

    // full 4-slot tables
    const bf16_t* ksrc4[4]; const bf16_t* vsrc4[4];
    int kdo4[4], vdo4[4];
    #pragma unroll
    for (int it = 0; it < 4; ++it) {
        const int slot = it * 512 + tid;
        {
            const int row  = slot >> 6;
            const int gseg = (slot & 63) ^ (row & 7);
            ksrc4[it] = kp + (size_t)row * 1024 + gseg * 8;
            kdo4[it]  = slot * 8;
        }
        {
            const int row  = slot >> 2;
            const int gseg = (slot & 3) ^ ((slot >> 3) & 3);
            vsrc4[it] = vp + (size_t)row * 2048 + gseg * 8;
            vdo4[it]  = slot * 8;
        }
    }

    auto stageK = [&](int bsel, int key0) {
        bf16_t* dst = Ks + bsel * (32 * 512);
        const size_t koff = (size_t)key0 * 1024;
        #pragma unroll
        for (int it = 0; it < 4; ++it)
            async_cp16(ksrc4[it] + koff, dst + kdo4[it]);
    };
    auto stageV = [&](int bsel, int key0) {
        bf16_t* dst = Vs + bsel * (512 * 32);
        #pragma unroll
        for (int it = 0; it < 4; ++it)
            async_cp16(vsrc4[it] + key0, dst + vdo4[it]);
    };

    // ---- stage tile 0, preload Q fragments (read exactly once) ----
    stageK(0, 0);
    stageV(0, 0);
    bf16x8 qreg[16];
    #pragma unroll
    for (int ks = 0; ks < 16; ++ks)
        qreg[ks] = *(const bf16x8*)(qp + (size_t)l16 * 1024 + ks * 32 + quad * 8);

    f32x4 o[4][8] = {};                   // O[ (qh*64 + rt*16) x (dw*128 + ct*16) ]
    float m_i[4], l_p[4];
    #pragma unroll
    for (int r = 0; r < 4; ++r) { m_i[r] = -10000.f; l_p[r] = 0.f; }

    const float scale = 0.0441941738241592f;  // 1/sqrt(512)
    const int   kx8   = l16 & 7;              // Ks read swizzle key
    const int   kx4   = (l16 >> 1) & 3;       // Vs/P read swizzle key (FIXED)

    __syncthreads();   // drains vmcnt(0): K(0), V(0) resident

    for (int kt = 0; kt < 64; ++kt) {
        const int b = kt & 1;
        const bf16_t* Kb = Ks + b * (32 * 512);
        const bf16_t* Vb = Vs + b * (512 * 32);

        // ---- prefetch tile t+1 into the other buffer (full-step window) ----
        const int nkey = ((kt + 1) & 63) * 32;   // wrap: last stage is dead data
        stageK(b ^ 1, nkey);
        stageV(b ^ 1, nkey);

        // ---- S = Q K^T : own 16 q-rows x 32 keys, K from swizzled LDS ----
        f32x4 s[2] = {};
        __builtin_amdgcn_s_setprio(1);
        #pragma unroll
        for (int ks = 0; ks < 16; ++ks) {
            #pragma unroll
            for (int j = 0; j < 2; ++j) {
                const bf16x8 kf = *(const bf16x8*)(Kb + (j * 16 + l16) * 512
                                                      + (((ks * 4 + quad) ^ kx8) * 8));
                s[j] = __builtin_amdgcn_mfma_f32_16x16x32_bf16(qreg[ks], kf, s[j], 0, 0, 0);
            }
        }
        __builtin_amdgcn_s_setprio(0);
        s[0] *= scale; s[1] *= scale;

        // ---- defer-max softmax: common path has NO cross-lane ops ----
        float own[4];
        #pragma unroll
        for (int r = 0; r < 4; ++r)
            own[r] = fmaxf(s[0][r], s[1][r]);
        const float g = fmaxf(fmaxf(own[0] - m_i[0], own[1] - m_i[1]),
                              fmaxf(own[2] - m_i[2], own[3] - m_i[3]));
        float alpha[4] = {1.f, 1.f, 1.f, 1.f};
        if (__any(g > 8.f)) {             // rare: step 0 + genuine max growth
            #pragma unroll
            for (int r = 0; r < 4; ++r) {
                float v = own[r];
                v = fmaxf(v, __shfl_xor(v, 1));
                v = fmaxf(v, __shfl_xor(v, 2));
                v = fmaxf(v, __shfl_xor(v, 4));
                v = fmaxf(v, __shfl_xor(v, 8));
                const float mn = fmaxf(m_i[r], v);
                alpha[r] = __expf(m_i[r] - mn);
                m_i[r] = mn;
                l_p[r] *= alpha[r];
            }
        }
        if (l16 == 0) {
            #pragma unroll
            for (int r = 0; r < 4; ++r)
                aLds[wave * 16 + quad * 4 + r] = alpha[r];
        }

        // ---- P = exp(S - m) -> swizzled LDS; l partial per lane ----
        #pragma unroll
        for (int j = 0; j < 2; ++j)
            #pragma unroll
            for (int r = 0; r < 4; ++r) {
                const float pe = __expf(s[j][r] - m_i[r]);   // bounded by e^8
                l_p[r] += pe;
                const int row = wave * 16 + quad * 4 + r;
                const int sg  = (j * 2 + (l16 >> 3)) ^ (((quad * 4 + r) >> 1) & 3);
                Plds[row * 32 + sg * 8 + (l16 & 7)] = (bf16_t)pe;
            }

        bar_lgkm();        // B1: P/alpha visible. NO vmcnt drain.

        // ---- rescale O by shared alphas (skipped when all 1 — common) ----
        #pragma unroll
        for (int rt = 0; rt < 4; ++rt) {
            const float a0 = aLds[qh * 64 + rt * 16 + quad * 4 + 0];
            const float a1 = aLds[qh * 64 + rt * 16 + quad * 4 + 1];
            const float a2 = aLds[qh * 64 + rt * 16 + quad * 4 + 2];
            const float a3 = aLds[qh * 64 + rt * 16 + quad * 4 + 3];
            if (a0 != 1.f || a1 != 1.f || a2 != 1.f || a3 != 1.f) {
                #pragma unroll
                for (int ct = 0; ct < 8; ++ct) {
                    f32x4 t = o[rt][ct];
                    t[0] *= a0; t[1] *= a1; t[2] *= a2; t[3] *= a3;
                    o[rt][ct] = t;
                }
            }
        }

        // ---- O += P V : wave tile [64q x 128d] ----
        __builtin_amdgcn_s_setprio(1);
        bf16x8 pa[4];
        #pragma unroll
        for (int rt = 0; rt < 4; ++rt)
            pa[rt] = *(const bf16x8*)(Plds + (qh * 64 + rt * 16 + l16) * 32
                                           + ((quad ^ kx4) * 8));
        #pragma unroll
        for (int ct = 0; ct < 8; ++ct) {
            const bf16x8 vf = *(const bf16x8*)(Vb + (dw * 128 + ct * 16 + l16) * 32
                                                  + ((quad ^ kx4) * 8));
            #pragma unroll
            for (int rt = 0; rt < 4; ++rt)
                o[rt][ct] = __builtin_amdgcn_mfma_f32_16x16x32_bf16(pa[rt], vf, o[rt][ct], 0, 0, 0);
        }
        __builtin_amdgcn_s_setprio(0);

        wait_vm0();        // tile t+1 fills landed (issued at step top)
        bar_lgkm();        // Bend: buffers b^1 ready; b free to restage
    }

    // ---- epilogue: reduce l partials once, share via LDS, write O ----
    #pragma unroll
    for (int r = 0; r < 4; ++r) {
        float t = l_p[r];
        t += __shfl_xor(t, 1);
        t += __shfl_xor(t, 2);
        t += __shfl_xor(t, 4);
        t += __shfl_xor(t, 8);
        if (l16 == 0) lLds[wave * 16 + quad * 4 + r] = t;
    }
    __syncthreads();

    const int b_out  = p / nH;
    const int coloff = (p % nH) * coloff_per_head + dw * 128;
    #pragma unroll
    for (int rt = 0; rt < 4; ++rt) {
        #pragma unroll
        for (int r = 0; r < 4; ++r) {
            const float linv = 1.f / lLds[qh * 64 + rt * 16 + quad * 4 + r];
            const int row = b_out * 2048 + qt * 128 + qh * 64 + rt * 16 + quad * 4 + r;
            #pragma unroll
            for (int ct = 0; ct < 8; ++ct)
                aout[(size_t)row * out_stride + coloff + ct * 16 + l16] =
                    (bf16_t)(o[rt][ct][r] * linv);
        }
    }
}

// ---------------------------------------------------------------------------
extern "C" void kernel_launch(void* const* d_in, const int* in_sizes, int n_in,
                              void* d_out, int out_size, void* d_ws, size_t ws_size,
                              hipStream_t stream)
{
    const float* x       = (const float*)d_in[0];  // [4096, 512]   f32
    const float* W_sep   = (const float*)d_in[1];  // [1536, 512]   f32
    const float* b_sep   = (const float*)d_in[2];  // [1536]        f32
    const float* W_multi = (const float*)d_in[3];  // [12288, 1536] f32
    const float* b_multi = (const float*)d_in[4];  // [12288]       f32
    const float* W_res   = (const float*)d_in[5];  // [512, 4096]   f32
    const float* b_res   = (const float*)d_in[6];  // [512]         f32
    float* out = (float*)d_out;                    // [4096, 512]   f32

    char* ws = (char*)d_ws;
    const dim3 blk(256);
    const dim3 ablk(512);

    if (ws_size >= 160956416ull) {
        // ------------- tier 1: 161 MB, whole-problem dispatches -------------
        bf16_t* wmb = (bf16_t*)(ws);                   // [12288,1536] 37.75 MB
        bf16_t* av  = (bf16_t*)(ws);                   // [4096,4096]  33.55 MB (over wmb, dead)
        bf16_t* xb  = (bf16_t*)(ws +  37748736ull);    // [4096,512]    4.19 MB
        bf16_t* wsb = (bf16_t*)(ws +  41943040ull);    // [1536,512]    1.57 MB
        bf16_t* wrb = (bf16_t*)(ws +  43515904ull);    // [512,4096]    4.19 MB
        bf16_t* h1  = (bf16_t*)(ws +  47710208ull);    // [4096,1536]  12.58 MB
        bf16_t* qk  = (bf16_t*)(ws +  60293120ull);    // [2,8,2048,1024] 67.11 MB
        bf16_t* vT  = (bf16_t*)(ws + 127401984ull);    // [2,8,512,2048]  33.55 MB

        f32_to_bf16<<<dim3( 2048), blk, 0, stream>>>(x,       xb,  2097152 / 4);
        f32_to_bf16<<<dim3(  768), blk, 0, stream>>>(W_sep,   wsb,  786432 / 4);
        f32_to_bf16<<<dim3(18432), blk, 0, stream>>>(W_multi, wmb, 18874368 / 4);
        f32_to_bf16<<<dim3( 2048), blk, 0, stream>>>(W_res,   wrb,  2097152 / 4);

        gemm_bt<<<dim3(12, 32), blk, 0, stream>>>(xb, 512, wsb, 512, b_sep,
                                                  h1, nullptr, 0, 1536, 512,
                                                  nullptr, nullptr, 0);
        gemm_bt<<<dim3(96, 32), blk, 0, stream>>>(h1, 1536, wmb, 1536, b_multi,
                                                  nullptr, nullptr, 0, 12288, 1536,
                                                  qk, vT, 8);
        attn<<<dim3(256), ablk, 0, stream>>>(qk, vT, av, 16, 8, 4096, 512);
        gemm_bt<<<dim3(4, 32), blk, 0, stream>>>(av, 4096, wrb, 4096, b_res,
                                                 nullptr, out, 1, 512, 4096,
                                                 nullptr, nullptr, 0);
    } else if (ws_size >= 39845888ull) {
        // ------------- tier 2: 39.8 MB, per-head streaming -------------
        bf16_t* h1    = (bf16_t*)(ws);                 // [4096,1536]  12.58 MB
        bf16_t* xb    = (bf16_t*)(ws + 12582912ull);   // [4096,512]    4.19 MB (dead after GEMM1)
        bf16_t* av_h  = (bf16_t*)(ws + 12582912ull);   //   reuse: [4096,512] bf16
        bf16_t* wsb   = (bf16_t*)(ws + 16777216ull);   // [1536,512]    1.57 MB
        bf16_t* wrb   = (bf16_t*)(ws + 18350080ull);   // [512,4096]    4.19 MB
        bf16_t* wmb_h = (bf16_t*)(ws + 22544384ull);   // [1536,1536]   4.72 MB
        bf16_t* qk_h  = (bf16_t*)(ws + 27262976ull);   // [2,2048,1024] 8.39 MB
        bf16_t* vT_h  = (bf16_t*)(ws + 35651584ull);   // [2,512,2048]  4.19 MB

        f32_to_bf16<<<dim3(2048), blk, 0, stream>>>(x,     xb,  2097152 / 4);
        f32_to_bf16<<<dim3( 768), blk, 0, stream>>>(W_sep, wsb,  786432 / 4);
        f32_to_bf16<<<dim3(2048), blk, 0, stream>>>(W_res, wrb,  2097152 / 4);

        gemm_bt<<<dim3(12, 32), blk, 0, stream>>>(xb, 512, wsb, 512, b_sep,
                                                  h1, nullptr, 0, 1536, 512,
                                                  nullptr, nullptr, 0);
        for (int h = 0; h < 8; ++h) {
            f32_to_bf16<<<dim3(2304), blk, 0, stream>>>(W_multi + (size_t)h * 1536 * 1536,
                                                        wmb_h, 2359296 / 4);
            gemm_bt<<<dim3(12, 32), blk, 0, stream>>>(h1, 1536, wmb_h, 1536,
                    b_multi + h * 1536, nullptr, nullptr, 0, 1536, 1536,
                    qk_h, vT_h, 1);
            attn<<<dim3(32), ablk, 0, stream>>>(qk_h, vT_h, av_h, 2, 1, 512, 0);
            gemm_bt<<<dim3(4, 32), blk, 0, stream>>>(av_h, 512, wrb + h * 512, 4096,
                    (h == 0) ? b_res : nullptr, nullptr, out, (h == 0) ? 1 : 0,
                    512, 512, nullptr, nullptr, 0);
        }
    } else {
        // ------------- tier 3: exactly 32 MiB, per-(batch,head) -------------
        bf16_t* h1    = (bf16_t*)(ws);                 // [4096,1536]  12.58 MB
        bf16_t* xb    = (bf16_t*)(ws + 12582912ull);   // [4096,512]    4.19 MB (dead after GEMM1)
        bf16_t* av_bh = (bf16_t*)(ws + 12582912ull);   //   reuse: [2048,512] bf16
        bf16_t* wsb   = (bf16_t*)(ws + 16777216ull);   // [1536,512]    1.57 MB
        bf16_t* wrb   = (bf16_t*)(ws + 18350080ull);   // [512,4096]    4.19 MB
        bf16_t* wmb_h = (bf16_t*)(ws + 22544384ull);   // [1536,1536]   4.72 MB
        bf16_t* qk_bh = (bf16_t*)(ws + 27262976ull);   // [2048,1024]   4.19 MB
        bf16_t* vT_bh = (bf16_t*)(ws + 31457280ull);   // [512,2048]    2.10 MB

        f32_to_bf16<<<dim3(2048), blk, 0, stream>>>(x,     xb,  2097152 / 4);
        f32_to_bf16<<<dim3( 768), blk, 0, stream>>>(W_sep, wsb,  786432 / 4);
        f32_to_bf16<<<dim3(2048), blk, 0, stream>>>(W_res, wrb,  2097152 / 4);

        gemm_bt<<<dim3(12, 32), blk, 0, stream>>>(xb, 512, wsb, 512, b_sep,
                                                  h1, nullptr, 0, 1536, 512,
                                                  nullptr, nullptr, 0);
        for (int h = 0; h < 8; ++h) {
            f32_to_bf16<<<dim3(2304), blk, 0, stream>>>(W_multi + (size_t)h * 1536 * 1536,
                                                        wmb_h, 2359296 / 4);
            for (int b = 0; b < 2; ++b) {
                gemm_bt<<<dim3(12, 16), blk, 0, stream>>>(h1 + (size_t)b * 2048 * 1536, 1536,
                        wmb_h, 1536, b_multi + h * 1536,
                        nullptr, nullptr, 0, 1536, 1536, qk_bh, vT_bh, 1);
                attn<<<dim3(16), ablk, 0, stream>>>(qk_bh, vT_bh, av_bh, 1, 1, 512, 0);
                gemm_bt<<<dim3(4, 16), blk, 0, stream>>>(av_bh, 512, wrb + h * 512, 4096,
                        (h == 0) ? b_res : nullptr, nullptr, out + (size_t)b * 2048 * 512,
                        (h == 0) ? 1 : 0, 512, 512, nullptr, nullptr, 0);
            }
        }
    }
}

// Round 5
// 762.074 us; speedup vs baseline: 1.1340x; 1.1340x over previous
//
#include <hip/hip_runtime.h>

// ============================================================================
// Attention_18923625906467 — MI355X (round 12)
//   out = ((x@Wsep^T)@Wmulti^T -> heads -> softmax(QK^T/sqrt(512))V) @ Wres^T
// B=2,S=2048,D=512,H=8.  f32 in/out; bf16 MFMA compute (2%-rel threshold).
//
// R11 post-mortem: attn conflict fix (2.5e7->1.68e7) did NOT move attn time
// (299 us) -> not conflict-bound. GEMM2 LDS-repack epilogue REGRESSED total
// by ~133 us (scatter writes were LLC-absorbed; repack added pure overhead).
// R12: (1) revert gemm_bt epilogue to R10 scalar scatter; (2) GEMM2 is
// cache-BW-bound (2.4 GB tile re-reads @ ~7 TB/s) -> new 256x256-tile
// gemm_bt256 (8 waves, acc[8][4], 2-barrier schedule, LDK=72) halves
// operand traffic; bijective XCD swizzle (768 blocks, 96/XCD) pins A-panels
// in per-XCD L2. attn unchanged (299 us).
// ============================================================================

typedef __bf16 bf16_t;
typedef __bf16 bf16x4 __attribute__((ext_vector_type(4)));
typedef __bf16 bf16x8 __attribute__((ext_vector_type(8)));
typedef float  f32x4  __attribute__((ext_vector_type(4)));

#define BM 128
#define BN 128
#define BK 64
#define LDK 72   // GEMM LDS row stride (bf16): 144B rows -> 2-way banks (free)

typedef const __attribute__((address_space(1))) void gvoid_t;
typedef __attribute__((address_space(3))) void svoid_t;

__device__ __forceinline__ void async_cp16(const bf16_t* g, bf16_t* l)
{
    __builtin_amdgcn_global_load_lds((gvoid_t*)g, (svoid_t*)l, 16, 0, 0);
}

__device__ __forceinline__ void bar_lgkm()
{
    asm volatile("s_waitcnt lgkmcnt(0)" ::: "memory");
    __builtin_amdgcn_s_barrier();
}

__device__ __forceinline__ void wait_vm0()
{
    asm volatile("s_waitcnt vmcnt(0)" ::: "memory");
}

// ---------------------------------------------------------------------------
__global__ void f32_to_bf16(const float* __restrict__ src, bf16_t* __restrict__ dst, int n4)
{
    const int i = blockIdx.x * 256 + threadIdx.x;
    if (i < n4) {
        const float4 v = ((const float4*)src)[i];
        bf16x4 o;
        o[0] = (bf16_t)v.x; o[1] = (bf16_t)v.y; o[2] = (bf16_t)v.z; o[3] = (bf16_t)v.w;
        ((bf16x4*)dst)[i] = o;
    }
}

// ---------------------------------------------------------------------------
// GEMM 128x128: D = A @ W^T + bias.  A:[M,lda], W:[N,ldw] row-major bf16.
//   C    != nullptr : write bf16 C[row*N+col]
//   Cacc != nullptr : f32 Cacc[row*N+col] = v (accFirst) or += v
//   qk   != nullptr : attention scatter (col = hh*1536 + off, row = bb*2048+ss):
//       off<1024 -> qk[((bb*hmul+hh)*2048+ss)*1024 + off]   (Q:0..511 K:512..1023)
//       else     -> vT[((bb*hmul+hh)*512+(off-1024))*2048 + ss]
// ---------------------------------------------------------------------------
__global__ __launch_bounds__(256, 2)
void gemm_bt(const bf16_t* __restrict__ A, int lda,
             const bf16_t* __restrict__ W, int ldw,
             const float* __restrict__ bias,
             bf16_t* __restrict__ C, float* __restrict__ Cacc, int accFirst,
             int N, int K,
             bf16_t* __restrict__ qk, bf16_t* __restrict__ vT, int hmul)
{
    __shared__ __align__(16) bf16_t As[BM * LDK];
    __shared__ __align__(16) bf16_t Ws[BN * LDK];

    const int tid  = threadIdx.x;
    const int wave = tid >> 6;
    const int lane = tid & 63;
    const int quad = lane >> 4;
    const int l16  = lane & 15;
    const int bm = blockIdx.y * BM;
    const int bn = blockIdx.x * BN;
    const int wm = (wave >> 1) * 64;
    const int wn = (wave & 1) * 64;

    f32x4 acc[4][4] = {};

    const int srow = tid >> 3;
    const int sseg = tid & 7;

    for (int k0 = 0; k0 < K; k0 += BK) {
        #pragma unroll
        for (int it = 0; it < 4; ++it) {
            const int row = it * 32 + srow;
            const int4 va = *(const int4*)(A + (size_t)(bm + row) * lda + k0 + sseg * 8);
            *(int4*)(As + row * LDK + sseg * 8) = va;
            const int4 vw = *(const int4*)(W + (size_t)(bn + row) * ldw + k0 + sseg * 8);
            *(int4*)(Ws + row * LDK + sseg * 8) = vw;
        }
        __syncthreads();
        #pragma unroll
        for (int kk = 0; kk < BK; kk += 32) {
            bf16x8 af[4], wf[4];
            #pragma unroll
            for (int i = 0; i < 4; ++i)
                af[i] = *(const bf16x8*)(As + (wm + i * 16 + l16) * LDK + kk + quad * 8);
            #pragma unroll
            for (int j = 0; j < 4; ++j)
                wf[j] = *(const bf16x8*)(Ws + (wn + j * 16 + l16) * LDK + kk + quad * 8);
            #pragma unroll
            for (int i = 0; i < 4; ++i)
                #pragma unroll
                for (int j = 0; j < 4; ++j)
                    acc[i][j] = __builtin_amdgcn_mfma_f32_16x16x32_bf16(af[i], wf[j], acc[i][j], 0, 0, 0);
        }
        __syncthreads();
    }

    #pragma unroll
    for (int j = 0; j < 4; ++j) {
        const int col = bn + wn + j * 16 + l16;
        const float bv = bias ? bias[col] : 0.f;
        #pragma unroll
        for (int i = 0; i < 4; ++i) {
            const int row0 = bm + wm + i * 16 + quad * 4;
            #pragma unroll
            for (int r = 0; r < 4; ++r) {
                const int row = row0 + r;
                const float v = acc[i][j][r] + bv;
                if (C)
                    C[(size_t)row * N + col] = (bf16_t)v;
                if (Cacc) {
                    const size_t idx = (size_t)row * N + col;
                    Cacc[idx] = accFirst ? v : (Cacc[idx] + v);
                }
                if (qk) {
                    const int hh  = col / 1536;
                    const int off = col - hh * 1536;
                    const int bb  = row >> 11;
                    const int ss  = row & 2047;
                    if (off < 1024)
                        qk[((size_t)((bb * hmul + hh) * 2048 + ss)) * 1024 + off] = (bf16_t)v;
                    else
                        vT[((size_t)((bb * hmul + hh) * 512 + (off - 1024))) * 2048 + ss] = (bf16_t)v;
                }
            }
        }
    }
}

// ---------------------------------------------------------------------------
// GEMM 256x256 (for the big GEMM2, cache-BW-bound): halves operand re-reads
// vs 128x128. 512 thr / 8 waves (2m x 4n), per-wave output 128x64 (acc[8][4]),
// same 2-barrier reg-staged schedule, LDK=72 (2-way banks, free).
// Bijective XCD swizzle: nwg must be divisible by 8 (768 for GEMM2) ->
// each XCD gets a contiguous chunk of 96 blocks = 2 full A-panel rows,
// pinning A-panels in its private L2.
// Epilogue: scalar qk/vT scatter (LLC-absorbed) or plain C.
// ---------------------------------------------------------------------------
__global__ __launch_bounds__(512, 2)
void gemm_bt256(const bf16_t* __restrict__ A, int lda,
                const bf16_t* __restrict__ W, int ldw,
                const float* __restrict__ bias,
                bf16_t* __restrict__ C, int N, int K,
                bf16_t* __restrict__ qk, bf16_t* __restrict__ vT, int hmul)
{
    __shared__ __align__(16) bf16_t As[256 * LDK];   // 36 KB
    __shared__ __align__(16) bf16_t Ws[256 * LDK];   // 36 KB

    const int tid  = threadIdx.x;
    const int wave = tid >> 6;
    const int lane = tid & 63;
    const int quad = lane >> 4;
    const int l16  = lane & 15;

    // ---- bijective XCD swizzle (nwg % 8 == 0) ----
    const int nwg = gridDim.x * gridDim.y;
    int bid = blockIdx.y * gridDim.x + blockIdx.x;
    const int cpx = nwg >> 3;
    bid = (bid & 7) * cpx + (bid >> 3);
    const int bm = (bid / gridDim.x) * 256;
    const int bn = (bid % gridDim.x) * 256;

    const int wm = (wave >> 2) * 128;   // 0 or 128
    const int wn = (wave & 3) * 64;     // 0..192

    f32x4 acc[8][4] = {};

    const int srow = tid >> 3;          // 0..63
    const int sseg = tid & 7;

    for (int k0 = 0; k0 < K; k0 += BK) {
        #pragma unroll
        for (int it = 0; it < 4; ++it) {
            const int row = it * 64 + srow;
            const int4 va = *(const int4*)(A + (size_t)(bm + row) * lda + k0 + sseg * 8);
            *(int4*)(As + row * LDK + sseg * 8) = va;
            const int4 vw = *(const int4*)(W + (size_t)(bn + row) * ldw + k0 + sseg * 8);
            *(int4*)(Ws + row * LDK + sseg * 8) = vw;
        }
        __syncthreads();
        #pragma unroll
        for (int kk = 0; kk < BK; kk += 32) {
            bf16x8 af[8], wf[4];
            #pragma unroll
            for (int i = 0; i < 8; ++i)
                af[i] = *(const bf16x8*)(As + (wm + i * 16 + l16) * LDK + kk + quad * 8);
            #pragma unroll
            for (int j = 0; j < 4; ++j)
                wf[j] = *(const bf16x8*)(Ws + (wn + j * 16 + l16) * LDK + kk + quad * 8);
            #pragma unroll
            for (int i = 0; i < 8; ++i)
                #pragma unroll
                for (int j = 0; j < 4; ++j)
                    acc[i][j] = __builtin_amdgcn_mfma_f32_16x16x32_bf16(af[i], wf[j], acc[i][j], 0, 0, 0);
        }
        __syncthreads();
    }

    #pragma unroll
    for (int j = 0; j < 4; ++j) {
        const int col = bn + wn + j * 16 + l16;
        const float bv = bias ? bias[col] : 0.f;
        #pragma unroll
        for (int i = 0; i < 8; ++i) {
            const int row0 = bm + wm + i * 16 + quad * 4;
            #pragma unroll
            for (int r = 0; r < 4; ++r) {
                const int row = row0 + r;
                const float v = acc[i][j][r] + bv;
                if (C)
                    C[(size_t)row * N + col] = (bf16_t)v;
                if (qk) {
                    const int hh  = col / 1536;
                    const int off = col - hh * 1536;
                    const int bb  = row >> 11;
                    const int ss  = row & 2047;
                    if (off < 1024)
                        qk[((size_t)((bb * hmul + hh) * 2048 + ss)) * 1024 + off] = (bf16_t)v;
                    else
                        vT[((size_t)((bb * hmul + hh) * 512 + (off - 1024))) * 2048 + ss] = (bf16_t)v;
                }
            }
        }
    }
}

// ---------------------------------------------------------------------------
// Flash attention (R11 structure, unchanged — 299 us measured).
// Grid nPairs*16 blocks x 512 thr (8 waves, 128 q-rows/block); 1 block/CU.
// KT=32 keys/step, 64 steps; K and V double-buffered in LDS.
// Per step t (buf b = t&1): issue stage(t+1)->buf b^1; QK; softmax
// (defer-max); P+alpha->LDS; B1 (lgkm only); rescale (guarded); PV;
// vmcnt(0); Bend.
// ---------------------------------------------------------------------------
__global__ __launch_bounds__(512, 2)
void attn(const bf16_t* __restrict__ qk, const bf16_t* __restrict__ vT,
          bf16_t* __restrict__ aout, int nPairs, int nH,
          int out_stride, int coloff_per_head)
{
    __shared__ __align__(16) bf16_t Ks[2 * 32 * 512];   // 64 KB
    __shared__ __align__(16) bf16_t Vs[2 * 512 * 32];   // 64 KB
    __shared__ __align__(16) bf16_t Plds[128 * 32];     //  8 KB
    __shared__ float aLds[128];
    __shared__ float lLds[128];

    const int tid  = threadIdx.x;
    const int wave = tid >> 6;
    const int lane = tid & 63;
    const int quad = lane >> 4;
    const int l16  = lane & 15;
    const int qh   = wave >> 2;       // PV q-half  (0..1)
    const int dw   = wave & 3;        // PV d-block (0..3)

    const int bid = blockIdx.x;
    const int p   = bid % nPairs;     // pair (b*nH + h)
    const int qt  = bid / nPairs;     // 0..15

    const bf16_t* qp = qk + ((size_t)(p * 2048 + qt * 128 + wave * 16)) * 1024;
    const bf16_t* kp = qk + ((size_t)(p * 2048)) * 1024 + 512;
    const bf16_t* vp = vT + (size_t)p * 512 * 2048;

    // ---- per-thread staging base addresses (hoisted) ----
    const bf16_t* ksrc4[4]; const bf16_t* vsrc4[4];
    int kdo4[4], vdo4[4];
    #pragma unroll
    for (int it = 0; it < 4; ++it) {
        const int slot = it * 512 + tid;
        {   // K: row = slot/64 (0..31); LDS[r][s] = G[r][s^(r&7)]
            const int row  = slot >> 6;
            const int gseg = (slot & 63) ^ (row & 7);
            ksrc4[it] = kp + (size_t)row * 1024 + gseg * 8;
            kdo4[it]  = slot * 8;
        }
        {   // V: row = slot/4 (0..511); LDS[r][s] = G[r][s^((r>>1)&3)]
            const int row  = slot >> 2;
            const int gseg = (slot & 3) ^ ((slot >> 3) & 3);
            vsrc4[it] = vp + (size_t)row * 2048 + gseg * 8;
            vdo4[it]  = slot * 8;
        }
    }

    auto stageK = [&](int bsel, int key0) {
        bf16_t* dst = Ks + bsel * (32 * 512);
        const size_t koff = (size_t)key0 * 1024;
        #pragma unroll
        for (int it = 0; it < 4; ++it)
            async_cp16(ksrc4[it] + koff, dst + kdo4[it]);
    };
    auto stageV = [&](int bsel, int key0) {
        bf16_t* dst = Vs + bsel * (512 * 32);
        #pragma unroll
        for (int it = 0; it < 4; ++it)
            async_cp16(vsrc4[it] + key0, dst + vdo4[it]);
    };

    // ---- stage tile 0, preload Q fragments (read exactly once) ----
    stageK(0, 0);
    stageV(0, 0);
    bf16x8 qreg[16];
    #pragma unroll
    for (int ks = 0; ks < 16; ++ks)
        qreg[ks] = *(const bf16x8*)(qp + (size_t)l16 * 1024 + ks * 32 + quad * 8);

    f32x4 o[4][8] = {};                   // O[ (qh*64 + rt*16) x (dw*128 + ct*16) ]
    float m_i[4], l_p[4];
    #pragma unroll
    for (int r = 0; r < 4; ++r) { m_i[r] = -10000.f; l_p[r] = 0.f; }

    const float scale = 0.0441941738241592f;  // 1/sqrt(512)
    const int   kx8   = l16 & 7;              // Ks read swizzle key
    const int   kx4   = (l16 >> 1) & 3;       // Vs/P read swizzle key

    __syncthreads();   // drains vmcnt(0): K(0), V(0) resident

    for (int kt = 0; kt < 64; ++kt) {
        const int b = kt & 1;
        const bf16_t* Kb = Ks + b * (32 * 512);
        const bf16_t* Vb = Vs + b * (512 * 32);

        // ---- prefetch tile t+1 into the other buffer (full-step window) ----
        const int nkey = ((kt + 1) & 63) * 32;   // wrap: last stage is dead data
        stageK(b ^ 1, nkey);
        stageV(b ^ 1, nkey);

        // ---- S = Q K^T : own 16 q-rows x 32 keys, K from swizzled LDS ----
        f32x4 s[2] = {};
        __builtin_amdgcn_s_setprio(1);
        #pragma unroll
        for (int ks = 0; ks < 16; ++ks) {
            #pragma unroll
            for (int j = 0; j < 2; ++j) {
                const bf16x8 kf = *(const bf16x8*)(Kb + (j * 16 + l16) * 512
                                                      + (((ks * 4 + quad) ^ kx8) * 8));
                s[j] = __builtin_amdgcn_mfma_f32_16x16x32_bf16(qreg[ks], kf, s[j], 0, 0, 0);
            }
        }
        __builtin_amdgcn_s_setprio(0);
        s[0] *= scale; s[1] *= scale;

        // ---- defer-max softmax: common path has NO cross-lane ops ----
        float own[4];
        #pragma unroll
        for (int r = 0; r < 4; ++r)
            own[r] = fmaxf(s[0][r], s[1][r]);
        const float g = fmaxf(fmaxf(own[0] - m_i[0], own[1] - m_i[1]),
                              fmaxf(own[2] - m_i[2], own[3] - m_i[3]));
        float alpha[4] = {1.f, 1.f, 1.f, 1.f};
        if (__any(g > 8.f)) {             // rare: step 0 + genuine max growth
            #pragma unroll
            for (int r = 0; r < 4; ++r) {
                float v = own[r];
                v = fmaxf(v, __shfl_xor(v, 1));
                v = fmaxf(v, __shfl_xor(v, 2));
                v = fmaxf(v, __shfl_xor(v, 4));
                v = fmaxf(v, __shfl_xor(v, 8));
                const float mn = fmaxf(m_i[r], v);
                alpha[r] = __expf(m_i[r] - mn);
                m_i[r] = mn;
                l_p[r] *= alpha[r];
            }
        }
        if (l16 == 0) {
            #pragma unroll
            for (int r = 0; r < 4; ++r)
                aLds[wave * 16 + quad * 4 + r] = alpha[r];
        }

        // ---- P = exp(S - m) -> swizzled LDS; l partial per lane ----
        #pragma unroll
        for (int j = 0; j < 2; ++j)
            #pragma unroll
            for (int r = 0; r < 4; ++r) {
                const float pe = __expf(s[j][r] - m_i[r]);   // bounded by e^8
                l_p[r] += pe;
                const int row = wave * 16 + quad * 4 + r;
                const int sg  = (j * 2 + (l16 >> 3)) ^ (((quad * 4 + r) >> 1) & 3);
                Plds[row * 32 + sg * 8 + (l16 & 7)] = (bf16_t)pe;
            }

        bar_lgkm();        // B1: P/alpha visible. NO vmcnt drain.

        // ---- rescale O by shared alphas (skipped when all 1 — common) ----
        #pragma unroll
        for (int rt = 0; rt < 4; ++rt) {
            const float a0 = aLds[qh * 64 + rt * 16 + quad * 4 + 0];
            const float a1 = aLds[qh * 64 + rt * 16 + quad * 4 + 1];
            const float a2 = aLds[qh * 64 + rt * 16 + quad * 4 + 2];
            const float a3 = aLds[qh * 64 + rt * 16 + quad * 4 + 3];
            if (a0 != 1.f || a1 != 1.f || a2 != 1.f || a3 != 1.f) {
                #pragma unroll
                for (int ct = 0; ct < 8; ++ct) {
                    f32x4 t = o[rt][ct];
                    t[0] *= a0; t[1] *= a1; t[2] *= a2; t[3] *= a3;
                    o[rt][ct] = t;
                }
            }
        }

        // ---- O += P V : wave tile [64q x 128d] ----
        __builtin_amdgcn_s_setprio(1);
        bf16x8 pa[4];
        #pragma unroll
        for (int rt = 0; rt < 4; ++rt)
            pa[rt] = *(const bf16x8*)(Plds + (qh * 64 + rt * 16 + l16) * 32
                                           + ((quad ^ kx4) * 8));
        #pragma unroll
        for (int ct = 0; ct < 8; ++ct) {
            const bf16x8 vf = *(const bf16x8*)(Vb + (dw * 128 + ct * 16 + l16) * 32
                                                  + ((quad ^ kx4) * 8));
            #pragma unroll
            for (int rt = 0; rt < 4; ++rt)
                o[rt][ct] = __builtin_amdgcn_mfma_f32_16x16x32_bf16(pa[rt], vf, o[rt][ct], 0, 0, 0);
        }
        __builtin_amdgcn_s_setprio(0);

        wait_vm0();        // tile t+1 fills landed (issued at step top)
        bar_lgkm();        // Bend: buffers b^1 ready; b free to restage
    }

    // ---- epilogue: reduce l partials once, share via LDS, write O ----
    #pragma unroll
    for (int r = 0; r < 4; ++r) {
        float t = l_p[r];
        t += __shfl_xor(t, 1);
        t += __shfl_xor(t, 2);
        t += __shfl_xor(t, 4);
        t += __shfl_xor(t, 8);
        if (l16 == 0) lLds[wave * 16 + quad * 4 + r] = t;
    }
    __syncthreads();

    const int b_out  = p / nH;
    const int coloff = (p % nH) * coloff_per_head + dw * 128;
    #pragma unroll
    for (int rt = 0; rt < 4; ++rt) {
        #pragma unroll
        for (int r = 0; r < 4; ++r) {
            const float linv = 1.f / lLds[qh * 64 + rt * 16 + quad * 4 + r];
            const int row = b_out * 2048 + qt * 128 + qh * 64 + rt * 16 + quad * 4 + r;
            #pragma unroll
            for (int ct = 0; ct < 8; ++ct)
                aout[(size_t)row * out_stride + coloff + ct * 16 + l16] =
                    (bf16_t)(o[rt][ct][r] * linv);
        }
    }
}

// ---------------------------------------------------------------------------
extern "C" void kernel_launch(void* const* d_in, const int* in_sizes, int n_in,
                              void* d_out, int out_size, void* d_ws, size_t ws_size,
                              hipStream_t stream)
{
    const float* x       = (const float*)d_in[0];  // [4096, 512]   f32
    const float* W_sep   = (const float*)d_in[1];  // [1536, 512]   f32
    const float* b_sep   = (const float*)d_in[2];  // [1536]        f32
    const float* W_multi = (const float*)d_in[3];  // [12288, 1536] f32
    const float* b_multi = (const float*)d_in[4];  // [12288]       f32
    const float* W_res   = (const float*)d_in[5];  // [512, 4096]   f32
    const float* b_res   = (const float*)d_in[6];  // [512]         f32
    float* out = (float*)d_out;                    // [4096, 512]   f32

    char* ws = (char*)d_ws;
    const dim3 blk(256);
    const dim3 ablk(512);

    if (ws_size >= 160956416ull) {
        // ------------- tier 1: 161 MB, whole-problem dispatches -------------
        bf16_t* wmb = (bf16_t*)(ws);                   // [12288,1536] 37.75 MB
        bf16_t* av  = (bf16_t*)(ws);                   // [4096,4096]  33.55 MB (over wmb, dead)
        bf16_t* xb  = (bf16_t*)(ws +  37748736ull);    // [4096,512]    4.19 MB
        bf16_t* wsb = (bf16_t*)(ws +  41943040ull);    // [1536,512]    1.57 MB
        bf16_t* wrb = (bf16_t*)(ws +  43515904ull);    // [512,4096]    4.19 MB
        bf16_t* h1  = (bf16_t*)(ws +  47710208ull);    // [4096,1536]  12.58 MB
        bf16_t* qk  = (bf16_t*)(ws +  60293120ull);    // [2,8,2048,1024] 67.11 MB
        bf16_t* vT  = (bf16_t*)(ws + 127401984ull);    // [2,8,512,2048]  33.55 MB

        f32_to_bf16<<<dim3( 2048), blk, 0, stream>>>(x,       xb,  2097152 / 4);
        f32_to_bf16<<<dim3(  768), blk, 0, stream>>>(W_sep,   wsb,  786432 / 4);
        f32_to_bf16<<<dim3(18432), blk, 0, stream>>>(W_multi, wmb, 18874368 / 4);
        f32_to_bf16<<<dim3( 2048), blk, 0, stream>>>(W_res,   wrb,  2097152 / 4);

        gemm_bt<<<dim3(12, 32), blk, 0, stream>>>(xb, 512, wsb, 512, b_sep,
                                                  h1, nullptr, 0, 1536, 512,
                                                  nullptr, nullptr, 0);
        gemm_bt256<<<dim3(48, 16), ablk, 0, stream>>>(h1, 1536, wmb, 1536, b_multi,
                                                      nullptr, 12288, 1536,
                                                      qk, vT, 8);
        attn<<<dim3(256), ablk, 0, stream>>>(qk, vT, av, 16, 8, 4096, 512);
        gemm_bt<<<dim3(4, 32), blk, 0, stream>>>(av, 4096, wrb, 4096, b_res,
                                                 nullptr, out, 1, 512, 4096,
                                                 nullptr, nullptr, 0);
    } else if (ws_size >= 39845888ull) {
        // ------------- tier 2: 39.8 MB, per-head streaming -------------
        bf16_t* h1    = (bf16_t*)(ws);                 // [4096,1536]  12.58 MB
        bf16_t* xb    = (bf16_t*)(ws + 12582912ull);   // [4096,512]    4.19 MB (dead after GEMM1)
        bf16_t* av_h  = (bf16_t*)(ws + 12582912ull);   //   reuse: [4096,512] bf16
        bf16_t* wsb   = (bf16_t*)(ws + 16777216ull);   // [1536,512]    1.57 MB
        bf16_t* wrb   = (bf16_t*)(ws + 18350080ull);   // [512,4096]    4.19 MB
        bf16_t* wmb_h = (bf16_t*)(ws + 22544384ull);   // [1536,1536]   4.72 MB
        bf16_t* qk_h  = (bf16_t*)(ws + 27262976ull);   // [2,2048,1024] 8.39 MB
        bf16_t* vT_h  = (bf16_t*)(ws + 35651584ull);   // [2,512,2048]  4.19 MB

        f32_to_bf16<<<dim3(2048), blk, 0, stream>>>(x,     xb,  2097152 / 4);
        f32_to_bf16<<<dim3( 768), blk, 0, stream>>>(W_sep, wsb,  786432 / 4);
        f32_to_bf16<<<dim3(2048), blk, 0, stream>>>(W_res, wrb,  2097152 / 4);

        gemm_bt<<<dim3(12, 32), blk, 0, stream>>>(xb, 512, wsb, 512, b_sep,
                                                  h1, nullptr, 0, 1536, 512,
                                                  nullptr, nullptr, 0);
        for (int h = 0; h < 8; ++h) {
            f32_to_bf16<<<dim3(2304), blk, 0, stream>>>(W_multi + (size_t)h * 1536 * 1536,
                                                        wmb_h, 2359296 / 4);
            gemm_bt<<<dim3(12, 32), blk, 0, stream>>>(h1, 1536, wmb_h, 1536,
                    b_multi + h * 1536, nullptr, nullptr, 0, 1536, 1536,
                    qk_h, vT_h, 1);
            attn<<<dim3(32), ablk, 0, stream>>>(qk_h, vT_h, av_h, 2, 1, 512, 0);
            gemm_bt<<<dim3(4, 32), blk, 0, stream>>>(av_h, 512, wrb + h * 512, 4096,
                    (h == 0) ? b_res : nullptr, nullptr, out, (h == 0) ? 1 : 0,
                    512, 512, nullptr, nullptr, 0);
        }
    } else {
        // ------------- tier 3: exactly 32 MiB, per-(batch,head) -------------
        bf16_t* h1    = (bf16_t*)(ws);                 // [4096,1536]  12.58 MB
        bf16_t* xb    = (bf16_t*)(ws + 12582912ull);   // [4096,512]    4.19 MB (dead after GEMM1)
        bf16_t* av_bh = (bf16_t*)(ws + 12582912ull);   //   reuse: [2048,512] bf16
        bf16_t* wsb   = (bf16_t*)(ws + 16777216ull);   // [1536,512]    1.57 MB
        bf16_t* wrb   = (bf16_t*)(ws + 18350080ull);   // [512,4096]    4.19 MB
        bf16_t* wmb_h = (bf16_t*)(ws + 22544384ull);   // [1536,1536]   4.72 MB
        bf16_t* qk_bh = (bf16_t*)(ws + 27262976ull);   // [2048,1024]   4.19 MB
        bf16_t* vT_bh = (bf16_t*)(ws + 31457280ull);   // [512,2048]    2.10 MB

        f32_to_bf16<<<dim3(2048), blk, 0, stream>>>(x,     xb,  2097152 / 4);
        f32_to_bf16<<<dim3( 768), blk, 0, stream>>>(W_sep, wsb,  786432 / 4);
        f32_to_bf16<<<dim3(2048), blk, 0, stream>>>(W_res, wrb,  2097152 / 4);

        gemm_bt<<<dim3(12, 32), blk, 0, stream>>>(xb, 512, wsb, 512, b_sep,
                                                  h1, nullptr, 0, 1536, 512,
                                                  nullptr, nullptr, 0);
        for (int h = 0; h < 8; ++h) {
            f32_to_bf16<<<dim3(2304), blk, 0, stream>>>(W_multi + (size_t)h * 1536 * 1536,
                                                        wmb_h, 2359296 / 4);
            for (int b = 0; b < 2; ++b) {
                gemm_bt<<<dim3(12, 16), blk, 0, stream>>>(h1 + (size_t)b * 2048 * 1536, 1536,
                        wmb_h, 1536, b_multi + h * 1536,
                        nullptr, nullptr, 0, 1536, 1536, qk_bh, vT_bh, 1);
                attn<<<dim3(16), ablk, 0, stream>>>(qk_bh, vT_bh, av_bh, 1, 1, 512, 0);
                gemm_bt<<<dim3(4, 16), blk, 0, stream>>>(av_bh, 512, wrb + h * 512, 4096,
                        (h == 0) ? b_res : nullptr, nullptr, out + (size_t)b * 2048 * 512,
                        (h == 0) ? 1 : 0, 512, 512, nullptr, nullptr, 0);
            }
        }
    }
}

// Round 6
// 697.623 us; speedup vs baseline: 1.2388x; 1.0924x over previous
//
#include <hip/hip_runtime.h>

// ============================================================================
// Attention_18923625906467 — MI355X (round 13)
//   out = ((x@Wsep^T)@Wmulti^T -> heads -> softmax(QK^T/sqrt(512))V) @ Wres^T
// B=2,S=2048,D=512,H=8.  f32 in/out; bf16 MFMA compute (2%-rel threshold).
//
// R12 post-mortem: 256^2 GEMM2 tile REGRESSED ~40 us vs 128^2 (acc alone =
// 128 VGPR -> 8 waves/CU; not cache-BW-bound after all). GEMM2 is the m151
// slow structure: reg-staged 2-barrier loop (~646 TF ceiling). R13 ports the
// session-proven attn R10 schedule to GEMM: gemm_db = 128^2 tile,
// global_load_lds staging (XOR-pre-swizzled source, linear LDS dest,
// conflict-free phase reads), K-tile double-buffer, stage(t+1) at step top,
// vmcnt(0) only AFTER compute, ONE barrier per K-step, XCD-chunked block
// swizzle. Used for GEMM1/2/3 everywhere. attn unchanged (290 us measured).
// ============================================================================

typedef __bf16 bf16_t;
typedef __bf16 bf16x4 __attribute__((ext_vector_type(4)));
typedef __bf16 bf16x8 __attribute__((ext_vector_type(8)));
typedef float  f32x4  __attribute__((ext_vector_type(4)));

#define BM 128
#define BN 128
#define BK 64

typedef const __attribute__((address_space(1))) void gvoid_t;
typedef __attribute__((address_space(3))) void svoid_t;

__device__ __forceinline__ void async_cp16(const bf16_t* g, bf16_t* l)
{
    __builtin_amdgcn_global_load_lds((gvoid_t*)g, (svoid_t*)l, 16, 0, 0);
}

__device__ __forceinline__ void bar_lgkm()
{
    asm volatile("s_waitcnt lgkmcnt(0)" ::: "memory");
    __builtin_amdgcn_s_barrier();
}

__device__ __forceinline__ void wait_vm0()
{
    asm volatile("s_waitcnt vmcnt(0)" ::: "memory");
}

// ---------------------------------------------------------------------------
__global__ void f32_to_bf16(const float* __restrict__ src, bf16_t* __restrict__ dst, int n4)
{
    const int i = blockIdx.x * 256 + threadIdx.x;
    if (i < n4) {
        const float4 v = ((const float4*)src)[i];
        bf16x4 o;
        o[0] = (bf16_t)v.x; o[1] = (bf16_t)v.y; o[2] = (bf16_t)v.z; o[3] = (bf16_t)v.w;
        ((bf16x4*)dst)[i] = o;
    }
}

// ---------------------------------------------------------------------------
// GEMM 128x128, double-buffered global_load_lds staging (attn-R10 schedule).
// D = A @ W^T + bias.  A:[M,lda], W:[N,ldw] row-major bf16, K%64==0.
// Grid must have (gridDim.x*gridDim.y) % 8 == 0 (bijective XCD swizzle).
//   C    != nullptr : write bf16 C[row*N+col]
//   Cacc != nullptr : f32 Cacc[row*N+col] = v (accFirst) or += v
//   qk   != nullptr : attention scatter (col = hh*1536 + off, row = bb*2048+ss):
//       off<1024 -> qk[((bb*hmul+hh)*2048+ss)*1024 + off]   (Q:0..511 K:512..1023)
//       else     -> vT[((bb*hmul+hh)*512+(off-1024))*2048 + ss]
// LDS layout per tile: [128 rows][8 segs of 16B]; seg s of row r holds global
// seg s^(r&7). Read seg = (kkseg+quad)^(l16&7): each consecutive-8-lane phase
// hits 8 distinct 16B slots -> conflict-free (same involution as attn Ks).
// ---------------------------------------------------------------------------
__global__ __launch_bounds__(256, 2)
void gemm_db(const bf16_t* __restrict__ A, int lda,
             const bf16_t* __restrict__ W, int ldw,
             const float* __restrict__ bias,
             bf16_t* __restrict__ C, float* __restrict__ Cacc, int accFirst,
             int N, int K,
             bf16_t* __restrict__ qk, bf16_t* __restrict__ vT, int hmul)
{
    __shared__ __align__(16) bf16_t Ls[2][2][BM * BK];   // [buf][A/W], 64 KB

    const int tid  = threadIdx.x;
    const int wave = tid >> 6;
    const int lane = tid & 63;
    const int quad = lane >> 4;
    const int l16  = lane & 15;

    // ---- bijective XCD swizzle: XCD c gets tiles [c*cpx, (c+1)*cpx) ----
    const int nwg = gridDim.x * gridDim.y;
    int bid = blockIdx.y * gridDim.x + blockIdx.x;
    bid = (bid & 7) * (nwg >> 3) + (bid >> 3);
    const int bm = (bid / gridDim.x) * BM;
    const int bn = (bid % gridDim.x) * BN;

    const int wm = (wave >> 1) * 64;
    const int wn = (wave & 1) * 64;

    // ---- staging bases: slot = it*256+tid; row = slot>>3; gs = (slot&7)^(row&7)
    const bf16_t* asrc[4]; const bf16_t* wsrc[4]; int ldo[4];
    #pragma unroll
    for (int it = 0; it < 4; ++it) {
        const int slot = it * 256 + tid;
        const int row  = slot >> 3;
        const int gs   = (slot & 7) ^ (row & 7);
        asrc[it] = A + (size_t)(bm + row) * lda + gs * 8;
        wsrc[it] = W + (size_t)(bn + row) * ldw + gs * 8;
        ldo[it]  = slot * 8;
    }

    auto stage = [&](int bsel, int k0) {
        bf16_t* da = &Ls[bsel][0][0];
        bf16_t* dw = &Ls[bsel][1][0];
        #pragma unroll
        for (int it = 0; it < 4; ++it) {
            async_cp16(asrc[it] + k0, da + ldo[it]);
            async_cp16(wsrc[it] + k0, dw + ldo[it]);
        }
    };

    f32x4 acc[4][4] = {};
    const int m7 = l16 & 7;

    stage(0, 0);
    wait_vm0();
    __syncthreads();

    const int nsteps = K / BK;
    for (int t = 0; t < nsteps; ++t) {
        const int b = t & 1;
        if (t + 1 < nsteps) stage(b ^ 1, (t + 1) * BK);   // full-step window

        const bf16_t* Ab = &Ls[b][0][0];
        const bf16_t* Wb = &Ls[b][1][0];
        __builtin_amdgcn_s_setprio(1);
        #pragma unroll
        for (int kk = 0; kk < 2; ++kk) {
            bf16x8 af[4], wf[4];
            #pragma unroll
            for (int i = 0; i < 4; ++i)
                af[i] = *(const bf16x8*)(Ab + (wm + i * 16 + l16) * BK
                                            + (((kk * 4 + quad) ^ m7) * 8));
            #pragma unroll
            for (int j = 0; j < 4; ++j)
                wf[j] = *(const bf16x8*)(Wb + (wn + j * 16 + l16) * BK
                                            + (((kk * 4 + quad) ^ m7) * 8));
            #pragma unroll
            for (int i = 0; i < 4; ++i)
                #pragma unroll
                for (int j = 0; j < 4; ++j)
                    acc[i][j] = __builtin_amdgcn_mfma_f32_16x16x32_bf16(af[i], wf[j], acc[i][j], 0, 0, 0);
        }
        __builtin_amdgcn_s_setprio(0);

        wait_vm0();        // tile t+1 landed (per-wave); barrier makes it global
        bar_lgkm();        // buf b free; buf b^1 fully resident for all waves
    }

    #pragma unroll
    for (int j = 0; j < 4; ++j) {
        const int col = bn + wn + j * 16 + l16;
        const float bv = bias ? bias[col] : 0.f;
        #pragma unroll
        for (int i = 0; i < 4; ++i) {
            const int row0 = bm + wm + i * 16 + quad * 4;
            #pragma unroll
            for (int r = 0; r < 4; ++r) {
                const int row = row0 + r;
                const float v = acc[i][j][r] + bv;
                if (C)
                    C[(size_t)row * N + col] = (bf16_t)v;
                if (Cacc) {
                    const size_t idx = (size_t)row * N + col;
                    Cacc[idx] = accFirst ? v : (Cacc[idx] + v);
                }
                if (qk) {
                    const int hh  = col / 1536;
                    const int off = col - hh * 1536;
                    const int bb  = row >> 11;
                    const int ss  = row & 2047;
                    if (off < 1024)
                        qk[((size_t)((bb * hmul + hh) * 2048 + ss)) * 1024 + off] = (bf16_t)v;
                    else
                        vT[((size_t)((bb * hmul + hh) * 512 + (off - 1024))) * 2048 + ss] = (bf16_t)v;
                }
            }
        }
    }
}

// ---------------------------------------------------------------------------
// Flash attention (R11 structure, unchanged — 290 us measured).
// Grid nPairs*16 blocks x 512 thr (8 waves, 128 q-rows/block); 1 block/CU.
// KT=32 keys/step, 64 steps; K and V double-buffered in LDS.
// Per step t (buf b = t&1): issue stage(t+1)->buf b^1; QK; softmax
// (defer-max); P+alpha->LDS; B1 (lgkm only); rescale (guarded); PV;
// vmcnt(0); Bend.
// ---------------------------------------------------------------------------
__global__ __launch_bounds__(512, 2)
void attn(const bf16_t* __restrict__ qk, const bf16_t* __restrict__ vT,
          bf16_t* __restrict__ aout, int nPairs, int nH,
          int out_stride, int coloff_per_head)
{
    __shared__ __align__(16) bf16_t Ks[2 * 32 * 512];   // 64 KB
    __shared__ __align__(16) bf16_t Vs[2 * 512 * 32];   // 64 KB
    __shared__ __align__(16) bf16_t Plds[128 * 32];     //  8 KB
    __shared__ float aLds[128];
    __shared__ float lLds[128];

    const int tid  = threadIdx.x;
    const int wave = tid >> 6;
    const int lane = tid & 63;
    const int quad = lane >> 4;
    const int l16  = lane & 15;
    const int qh   = wave >> 2;       // PV q-half  (0..1)
    const int dw   = wave & 3;        // PV d-block (0..3)

    const int bid = blockIdx.x;
    const int p   = bid % nPairs;     // pair (b*nH + h)
    const int qt  = bid / nPairs;     // 0..15

    const bf16_t* qp = qk + ((size_t)(p * 2048 + qt * 128 + wave * 16)) * 1024;
    const bf16_t* kp = qk + ((size_t)(p * 2048)) * 1024 + 512;
    const bf16_t* vp = vT + (size_t)p * 512 * 2048;

    // ---- per-thread staging base addresses (hoisted) ----
    const bf16_t* ksrc4[4]; const bf16_t* vsrc4[4];
    int kdo4[4], vdo4[4];
    #pragma unroll
    for (int it = 0; it < 4; ++it) {
        const int slot = it * 512 + tid;
        {   // K: row = slot/64 (0..31); LDS[r][s] = G[r][s^(r&7)]
            const int row  = slot >> 6;
            const int gseg = (slot & 63) ^ (row & 7);
            ksrc4[it] = kp + (size_t)row * 1024 + gseg * 8;
            kdo4[it]  = slot * 8;
        }
        {   // V: row = slot/4 (0..511); LDS[r][s] = G[r][s^((r>>1)&3)]
            const int row  = slot >> 2;
            const int gseg = (slot & 3) ^ ((slot >> 3) & 3);
            vsrc4[it] = vp + (size_t)row * 2048 + gseg * 8;
            vdo4[it]  = slot * 8;
        }
    }

    auto stageK = [&](int bsel, int key0) {
        bf16_t* dst = Ks + bsel * (32 * 512);
        const size_t koff = (size_t)key0 * 1024;
        #pragma unroll
        for (int it = 0; it < 4; ++it)
            async_cp16(ksrc4[it] + koff, dst + kdo4[it]);
    };
    auto stageV = [&](int bsel, int key0) {
        bf16_t* dst = Vs + bsel * (512 * 32);
        #pragma unroll
        for (int it = 0; it < 4; ++it)
            async_cp16(vsrc4[it] + key0, dst + vdo4[it]);
    };

    // ---- stage tile 0, preload Q fragments (read exactly once) ----
    stageK(0, 0);
    stageV(0, 0);
    bf16x8 qreg[16];
    #pragma unroll
    for (int ks = 0; ks < 16; ++ks)
        qreg[ks] = *(const bf16x8*)(qp + (size_t)l16 * 1024 + ks * 32 + quad * 8);

    f32x4 o[4][8] = {};                   // O[ (qh*64 + rt*16) x (dw*128 + ct*16) ]
    float m_i[4], l_p[4];
    #pragma unroll
    for (int r = 0; r < 4; ++r) { m_i[r] = -10000.f; l_p[r] = 0.f; }

    const float scale = 0.0441941738241592f;  // 1/sqrt(512)
    const int   kx8   = l16 & 7;              // Ks read swizzle key
    const int   kx4   = (l16 >> 1) & 3;       // Vs/P read swizzle key

    __syncthreads();   // drains vmcnt(0): K(0), V(0) resident

    for (int kt = 0; kt < 64; ++kt) {
        const int b = kt & 1;
        const bf16_t* Kb = Ks + b * (32 * 512);
        const bf16_t* Vb = Vs + b * (512 * 32);

        // ---- prefetch tile t+1 into the other buffer (full-step window) ----
        const int nkey = ((kt + 1) & 63) * 32;   // wrap: last stage is dead data
        stageK(b ^ 1, nkey);
        stageV(b ^ 1, nkey);

        // ---- S = Q K^T : own 16 q-rows x 32 keys, K from swizzled LDS ----
        f32x4 s[2] = {};
        __builtin_amdgcn_s_setprio(1);
        #pragma unroll
        for (int ks = 0; ks < 16; ++ks) {
            #pragma unroll
            for (int j = 0; j < 2; ++j) {
                const bf16x8 kf = *(const bf16x8*)(Kb + (j * 16 + l16) * 512
                                                      + (((ks * 4 + quad) ^ kx8) * 8));
                s[j] = __builtin_amdgcn_mfma_f32_16x16x32_bf16(qreg[ks], kf, s[j], 0, 0, 0);
            }
        }
        __builtin_amdgcn_s_setprio(0);
        s[0] *= scale; s[1] *= scale;

        // ---- defer-max softmax: common path has NO cross-lane ops ----
        float own[4];
        #pragma unroll
        for (int r = 0; r < 4; ++r)
            own[r] = fmaxf(s[0][r], s[1][r]);
        const float g = fmaxf(fmaxf(own[0] - m_i[0], own[1] - m_i[1]),
                              fmaxf(own[2] - m_i[2], own[3] - m_i[3]));
        float alpha[4] = {1.f, 1.f, 1.f, 1.f};
        if (__any(g > 8.f)) {             // rare: step 0 + genuine max growth
            #pragma unroll
            for (int r = 0; r < 4; ++r) {
                float v = own[r];
                v = fmaxf(v, __shfl_xor(v, 1));
                v = fmaxf(v, __shfl_xor(v, 2));
                v = fmaxf(v, __shfl_xor(v, 4));
                v = fmaxf(v, __shfl_xor(v, 8));
                const float mn = fmaxf(m_i[r], v);
                alpha[r] = __expf(m_i[r] - mn);
                m_i[r] = mn;
                l_p[r] *= alpha[r];
            }
        }
        if (l16 == 0) {
            #pragma unroll
            for (int r = 0; r < 4; ++r)
                aLds[wave * 16 + quad * 4 + r] = alpha[r];
        }

        // ---- P = exp(S - m) -> swizzled LDS; l partial per lane ----
        #pragma unroll
        for (int j = 0; j < 2; ++j)
            #pragma unroll
            for (int r = 0; r < 4; ++r) {
                const float pe = __expf(s[j][r] - m_i[r]);   // bounded by e^8
                l_p[r] += pe;
                const int row = wave * 16 + quad * 4 + r;
                const int sg  = (j * 2 + (l16 >> 3)) ^ (((quad * 4 + r) >> 1) & 3);
                Plds[row * 32 + sg * 8 + (l16 & 7)] = (bf16_t)pe;
            }

        bar_lgkm();        // B1: P/alpha visible. NO vmcnt drain.

        // ---- rescale O by shared alphas (skipped when all 1 — common) ----
        #pragma unroll
        for (int rt = 0; rt < 4; ++rt) {
            const float a0 = aLds[qh * 64 + rt * 16 + quad * 4 + 0];
            const float a1 = aLds[qh * 64 + rt * 16 + quad * 4 + 1];
            const float a2 = aLds[qh * 64 + rt * 16 + quad * 4 + 2];
            const float a3 = aLds[qh * 64 + rt * 16 + quad * 4 + 3];
            if (a0 != 1.f || a1 != 1.f || a2 != 1.f || a3 != 1.f) {
                #pragma unroll
                for (int ct = 0; ct < 8; ++ct) {
                    f32x4 t = o[rt][ct];
                    t[0] *= a0; t[1] *= a1; t[2] *= a2; t[3] *= a3;
                    o[rt][ct] = t;
                }
            }
        }

        // ---- O += P V : wave tile [64q x 128d] ----
        __builtin_amdgcn_s_setprio(1);
        bf16x8 pa[4];
        #pragma unroll
        for (int rt = 0; rt < 4; ++rt)
            pa[rt] = *(const bf16x8*)(Plds + (qh * 64 + rt * 16 + l16) * 32
                                           + ((quad ^ kx4) * 8));
        #pragma unroll
        for (int ct = 0; ct < 8; ++ct) {
            const bf16x8 vf = *(const bf16x8*)(Vb + (dw * 128 + ct * 16 + l16) * 32
                                                  + ((quad ^ kx4) * 8));
            #pragma unroll
            for (int rt = 0; rt < 4; ++rt)
                o[rt][ct] = __builtin_amdgcn_mfma_f32_16x16x32_bf16(pa[rt], vf, o[rt][ct], 0, 0, 0);
        }
        __builtin_amdgcn_s_setprio(0);

        wait_vm0();        // tile t+1 fills landed (issued at step top)
        bar_lgkm();        // Bend: buffers b^1 ready; b free to restage
    }

    // ---- epilogue: reduce l partials once, share via LDS, write O ----
    #pragma unroll
    for (int r = 0; r < 4; ++r) {
        float t = l_p[r];
        t += __shfl_xor(t, 1);
        t += __shfl_xor(t, 2);
        t += __shfl_xor(t, 4);
        t += __shfl_xor(t, 8);
        if (l16 == 0) lLds[wave * 16 + quad * 4 + r] = t;
    }
    __syncthreads();

    const int b_out  = p / nH;
    const int coloff = (p % nH) * coloff_per_head + dw * 128;
    #pragma unroll
    for (int rt = 0; rt < 4; ++rt) {
        #pragma unroll
        for (int r = 0; r < 4; ++r) {
            const float linv = 1.f / lLds[qh * 64 + rt * 16 + quad * 4 + r];
            const int row = b_out * 2048 + qt * 128 + qh * 64 + rt * 16 + quad * 4 + r;
            #pragma unroll
            for (int ct = 0; ct < 8; ++ct)
                aout[(size_t)row * out_stride + coloff + ct * 16 + l16] =
                    (bf16_t)(o[rt][ct][r] * linv);
        }
    }
}

// ---------------------------------------------------------------------------
extern "C" void kernel_launch(void* const* d_in, const int* in_sizes, int n_in,
                              void* d_out, int out_size, void* d_ws, size_t ws_size,
                              hipStream_t stream)
{
    const float* x       = (const float*)d_in[0];  // [4096, 512]   f32
    const float* W_sep   = (const float*)d_in[1];  // [1536, 512]   f32
    const float* b_sep   = (const float*)d_in[2];  // [1536]        f32
    const float* W_multi = (const float*)d_in[3];  // [12288, 1536] f32
    const float* b_multi = (const float*)d_in[4];  // [12288]       f32
    const float* W_res   = (const float*)d_in[5];  // [512, 4096]   f32
    const float* b_res   = (const float*)d_in[6];  // [512]         f32
    float* out = (float*)d_out;                    // [4096, 512]   f32

    char* ws = (char*)d_ws;
    const dim3 blk(256);
    const dim3 ablk(512);

    if (ws_size >= 160956416ull) {
        // ------------- tier 1: 161 MB, whole-problem dispatches -------------
        bf16_t* wmb = (bf16_t*)(ws);                   // [12288,1536] 37.75 MB
        bf16_t* av  = (bf16_t*)(ws);                   // [4096,4096]  33.55 MB (over wmb, dead)
        bf16_t* xb  = (bf16_t*)(ws +  37748736ull);    // [4096,512]    4.19 MB
        bf16_t* wsb = (bf16_t*)(ws +  41943040ull);    // [1536,512]    1.57 MB
        bf16_t* wrb = (bf16_t*)(ws +  43515904ull);    // [512,4096]    4.19 MB
        bf16_t* h1  = (bf16_t*)(ws +  47710208ull);    // [4096,1536]  12.58 MB
        bf16_t* qk  = (bf16_t*)(ws +  60293120ull);    // [2,8,2048,1024] 67.11 MB
        bf16_t* vT  = (bf16_t*)(ws + 127401984ull);    // [2,8,512,2048]  33.55 MB

        f32_to_bf16<<<dim3( 2048), blk, 0, stream>>>(x,       xb,  2097152 / 4);
        f32_to_bf16<<<dim3(  768), blk, 0, stream>>>(W_sep,   wsb,  786432 / 4);
        f32_to_bf16<<<dim3(18432), blk, 0, stream>>>(W_multi, wmb, 18874368 / 4);
        f32_to_bf16<<<dim3( 2048), blk, 0, stream>>>(W_res,   wrb,  2097152 / 4);

        gemm_db<<<dim3(12, 32), blk, 0, stream>>>(xb, 512, wsb, 512, b_sep,
                                                  h1, nullptr, 0, 1536, 512,
                                                  nullptr, nullptr, 0);
        gemm_db<<<dim3(96, 32), blk, 0, stream>>>(h1, 1536, wmb, 1536, b_multi,
                                                  nullptr, nullptr, 0, 12288, 1536,
                                                  qk, vT, 8);
        attn<<<dim3(256), ablk, 0, stream>>>(qk, vT, av, 16, 8, 4096, 512);
        gemm_db<<<dim3(4, 32), blk, 0, stream>>>(av, 4096, wrb, 4096, b_res,
                                                 nullptr, out, 1, 512, 4096,
                                                 nullptr, nullptr, 0);
    } else if (ws_size >= 39845888ull) {
        // ------------- tier 2: 39.8 MB, per-head streaming -------------
        bf16_t* h1    = (bf16_t*)(ws);                 // [4096,1536]  12.58 MB
        bf16_t* xb    = (bf16_t*)(ws + 12582912ull);   // [4096,512]    4.19 MB (dead after GEMM1)
        bf16_t* av_h  = (bf16_t*)(ws + 12582912ull);   //   reuse: [4096,512] bf16
        bf16_t* wsb   = (bf16_t*)(ws + 16777216ull);   // [1536,512]    1.57 MB
        bf16_t* wrb   = (bf16_t*)(ws + 18350080ull);   // [512,4096]    4.19 MB
        bf16_t* wmb_h = (bf16_t*)(ws + 22544384ull);   // [1536,1536]   4.72 MB
        bf16_t* qk_h  = (bf16_t*)(ws + 27262976ull);   // [2,2048,1024] 8.39 MB
        bf16_t* vT_h  = (bf16_t*)(ws + 35651584ull);   // [2,512,2048]  4.19 MB

        f32_to_bf16<<<dim3(2048), blk, 0, stream>>>(x,     xb,  2097152 / 4);
        f32_to_bf16<<<dim3( 768), blk, 0, stream>>>(W_sep, wsb,  786432 / 4);
        f32_to_bf16<<<dim3(2048), blk, 0, stream>>>(W_res, wrb,  2097152 / 4);

        gemm_db<<<dim3(12, 32), blk, 0, stream>>>(xb, 512, wsb, 512, b_sep,
                                                  h1, nullptr, 0, 1536, 512,
                                                  nullptr, nullptr, 0);
        for (int h = 0; h < 8; ++h) {
            f32_to_bf16<<<dim3(2304), blk, 0, stream>>>(W_multi + (size_t)h * 1536 * 1536,
                                                        wmb_h, 2359296 / 4);
            gemm_db<<<dim3(12, 32), blk, 0, stream>>>(h1, 1536, wmb_h, 1536,
                    b_multi + h * 1536, nullptr, nullptr, 0, 1536, 1536,
                    qk_h, vT_h, 1);
            attn<<<dim3(32), ablk, 0, stream>>>(qk_h, vT_h, av_h, 2, 1, 512, 0);
            gemm_db<<<dim3(4, 32), blk, 0, stream>>>(av_h, 512, wrb + h * 512, 4096,
                    (h == 0) ? b_res : nullptr, nullptr, out, (h == 0) ? 1 : 0,
                    512, 512, nullptr, nullptr, 0);
        }
    } else {
        // ------------- tier 3: exactly 32 MiB, per-(batch,head) -------------
        bf16_t* h1    = (bf16_t*)(ws);                 // [4096,1536]  12.58 MB
        bf16_t* xb    = (bf16_t*)(ws + 12582912ull);   // [4096,512]    4.19 MB (dead after GEMM1)
        bf16_t* av_bh = (bf16_t*)(ws + 12582912ull);   //   reuse: [2048,512] bf16
        bf16_t* wsb   = (bf16_t*)(ws + 16777216ull);   // [1536,512]    1.57 MB
        bf16_t* wrb   = (bf16_t*)(ws + 18350080ull);   // [512,4096]    4.19 MB
        bf16_t* wmb_h = (bf16_t*)(ws + 22544384ull);   // [1536,1536]   4.72 MB
        bf16_t* qk_bh = (bf16_t*)(ws + 27262976ull);   // [2048,1024]   4.19 MB
        bf16_t* vT_bh = (bf16_t*)(ws + 31457280ull);   // [512,2048]    2.10 MB

        f32_to_bf16<<<dim3(2048), blk, 0, stream>>>(x,     xb,  2097152 / 4);
        f32_to_bf16<<<dim3( 768), blk, 0, stream>>>(W_sep, wsb,  786432 / 4);
        f32_to_bf16<<<dim3(2048), blk, 0, stream>>>(W_res, wrb,  2097152 / 4);

        gemm_db<<<dim3(12, 32), blk, 0, stream>>>(xb, 512, wsb, 512, b_sep,
                                                  h1, nullptr, 0, 1536, 512,
                                                  nullptr, nullptr, 0);
        for (int h = 0; h < 8; ++h) {
            f32_to_bf16<<<dim3(2304), blk, 0, stream>>>(W_multi + (size_t)h * 1536 * 1536,
                                                        wmb_h, 2359296 / 4);
            for (int b = 0; b < 2; ++b) {
                gemm_db<<<dim3(12, 16), blk, 0, stream>>>(h1 + (size_t)b * 2048 * 1536, 1536,
                        wmb_h, 1536, b_multi + h * 1536,
                        nullptr, nullptr, 0, 1536, 1536, qk_bh, vT_bh, 1);
                attn<<<dim3(16), ablk, 0, stream>>>(qk_bh, vT_bh, av_bh, 1, 1, 512, 0);
                gemm_db<<<dim3(4, 16), blk, 0, stream>>>(av_bh, 512, wrb + h * 512, 4096,
                        (h == 0) ? b_res : nullptr, nullptr, out + (size_t)b * 2048 * 512,
                        (h == 0) ? 1 : 0, 512, 512, nullptr, nullptr, 0);
            }
        }
    }
}

// Round 7
// 659.030 us; speedup vs baseline: 1.3114x; 1.0586x over previous
//
#include <hip/hip_runtime.h>

// ============================================================================
// Attention_18923625906467 — MI355X (round 14)
//   out = ((x@Wsep^T)@Wmulti^T -> heads -> softmax(QK^T/sqrt(512))V) @ Wres^T
// B=2,S=2048,D=512,H=8.  f32 in/out; bf16 MFMA compute (2%-rel threshold).
//
// R13: gemm_db (gload_lds + counted-drain dbuf) gained ~65 us; attn 292 us.
// R14: (1) gemm_db256 for GEMM2: same proven schedule at 256^2 tile ->
//     operand traffic 2.36 GB -> 1.18 GB, MFMA:ds_read 64:24 vs 32:16,
//     n-major XCD chunking pins 6 W-panels (4.6 MB) per XCD L2.
//     (R12's 256^2 failed due to reg-staged structure, not tile size.)
// (2) attn XCD pair-grouping: XCD c gets pairs {2c,2c+1} (contiguous
//     32-block work chunks) -> per-XCD K/V working set 64 MB -> 8 MB.
//     Schedule untouched.
// ============================================================================

typedef __bf16 bf16_t;
typedef __bf16 bf16x4 __attribute__((ext_vector_type(4)));
typedef __bf16 bf16x8 __attribute__((ext_vector_type(8)));
typedef float  f32x4  __attribute__((ext_vector_type(4)));

#define BM 128
#define BN 128
#define BK 64

typedef const __attribute__((address_space(1))) void gvoid_t;
typedef __attribute__((address_space(3))) void svoid_t;

__device__ __forceinline__ void async_cp16(const bf16_t* g, bf16_t* l)
{
    __builtin_amdgcn_global_load_lds((gvoid_t*)g, (svoid_t*)l, 16, 0, 0);
}

__device__ __forceinline__ void bar_lgkm()
{
    asm volatile("s_waitcnt lgkmcnt(0)" ::: "memory");
    __builtin_amdgcn_s_barrier();
}

__device__ __forceinline__ void wait_vm0()
{
    asm volatile("s_waitcnt vmcnt(0)" ::: "memory");
}

// ---------------------------------------------------------------------------
__global__ void f32_to_bf16(const float* __restrict__ src, bf16_t* __restrict__ dst, int n4)
{
    const int i = blockIdx.x * 256 + threadIdx.x;
    if (i < n4) {
        const float4 v = ((const float4*)src)[i];
        bf16x4 o;
        o[0] = (bf16_t)v.x; o[1] = (bf16_t)v.y; o[2] = (bf16_t)v.z; o[3] = (bf16_t)v.w;
        ((bf16x4*)dst)[i] = o;
    }
}

// ---------------------------------------------------------------------------
// GEMM 128x128, double-buffered global_load_lds staging (attn-R10 schedule).
// D = A @ W^T + bias.  A:[M,lda], W:[N,ldw] row-major bf16, K%64==0.
// Grid must have (gridDim.x*gridDim.y) % 8 == 0 (bijective XCD swizzle).
//   C    != nullptr : write bf16 C[row*N+col]
//   Cacc != nullptr : f32 Cacc[row*N+col] = v (accFirst) or += v
//   qk   != nullptr : attention scatter (col = hh*1536 + off, row = bb*2048+ss):
//       off<1024 -> qk[((bb*hmul+hh)*2048+ss)*1024 + off]   (Q:0..511 K:512..1023)
//       else     -> vT[((bb*hmul+hh)*512+(off-1024))*2048 + ss]
// LDS per tile: [128 rows][8 segs]; seg s of row r holds global seg s^(r&7).
// Read seg = (kkseg+quad)^(l16&7) -> conflict-free phases.
// ---------------------------------------------------------------------------
__global__ __launch_bounds__(256, 2)
void gemm_db(const bf16_t* __restrict__ A, int lda,
             const bf16_t* __restrict__ W, int ldw,
             const float* __restrict__ bias,
             bf16_t* __restrict__ C, float* __restrict__ Cacc, int accFirst,
             int N, int K,
             bf16_t* __restrict__ qk, bf16_t* __restrict__ vT, int hmul)
{
    __shared__ __align__(16) bf16_t Ls[2][2][BM * BK];   // [buf][A/W], 64 KB

    const int tid  = threadIdx.x;
    const int wave = tid >> 6;
    const int lane = tid & 63;
    const int quad = lane >> 4;
    const int l16  = lane & 15;

    // ---- bijective XCD swizzle: XCD c gets tiles [c*cpx, (c+1)*cpx) ----
    const int nwg = gridDim.x * gridDim.y;
    int bid = blockIdx.y * gridDim.x + blockIdx.x;
    bid = (bid & 7) * (nwg >> 3) + (bid >> 3);
    const int bm = (bid / gridDim.x) * BM;
    const int bn = (bid % gridDim.x) * BN;

    const int wm = (wave >> 1) * 64;
    const int wn = (wave & 1) * 64;

    // ---- staging bases: slot = it*256+tid; row = slot>>3; gs = (slot&7)^(row&7)
    const bf16_t* asrc[4]; const bf16_t* wsrc[4]; int ldo[4];
    #pragma unroll
    for (int it = 0; it < 4; ++it) {
        const int slot = it * 256 + tid;
        const int row  = slot >> 3;
        const int gs   = (slot & 7) ^ (row & 7);
        asrc[it] = A + (size_t)(bm + row) * lda + gs * 8;
        wsrc[it] = W + (size_t)(bn + row) * ldw + gs * 8;
        ldo[it]  = slot * 8;
    }

    auto stage = [&](int bsel, int k0) {
        bf16_t* da = &Ls[bsel][0][0];
        bf16_t* dw = &Ls[bsel][1][0];
        #pragma unroll
        for (int it = 0; it < 4; ++it) {
            async_cp16(asrc[it] + k0, da + ldo[it]);
            async_cp16(wsrc[it] + k0, dw + ldo[it]);
        }
    };

    f32x4 acc[4][4] = {};
    const int m7 = l16 & 7;

    stage(0, 0);
    wait_vm0();
    __syncthreads();

    const int nsteps = K / BK;
    for (int t = 0; t < nsteps; ++t) {
        const int b = t & 1;
        if (t + 1 < nsteps) stage(b ^ 1, (t + 1) * BK);   // full-step window

        const bf16_t* Ab = &Ls[b][0][0];
        const bf16_t* Wb = &Ls[b][1][0];
        __builtin_amdgcn_s_setprio(1);
        #pragma unroll
        for (int kk = 0; kk < 2; ++kk) {
            bf16x8 af[4], wf[4];
            #pragma unroll
            for (int i = 0; i < 4; ++i)
                af[i] = *(const bf16x8*)(Ab + (wm + i * 16 + l16) * BK
                                            + (((kk * 4 + quad) ^ m7) * 8));
            #pragma unroll
            for (int j = 0; j < 4; ++j)
                wf[j] = *(const bf16x8*)(Wb + (wn + j * 16 + l16) * BK
                                            + (((kk * 4 + quad) ^ m7) * 8));
            #pragma unroll
            for (int i = 0; i < 4; ++i)
                #pragma unroll
                for (int j = 0; j < 4; ++j)
                    acc[i][j] = __builtin_amdgcn_mfma_f32_16x16x32_bf16(af[i], wf[j], acc[i][j], 0, 0, 0);
        }
        __builtin_amdgcn_s_setprio(0);

        wait_vm0();        // tile t+1 landed (per-wave); barrier makes it global
        bar_lgkm();        // buf b free; buf b^1 fully resident for all waves
    }

    #pragma unroll
    for (int j = 0; j < 4; ++j) {
        const int col = bn + wn + j * 16 + l16;
        const float bv = bias ? bias[col] : 0.f;
        #pragma unroll
        for (int i = 0; i < 4; ++i) {
            const int row0 = bm + wm + i * 16 + quad * 4;
            #pragma unroll
            for (int r = 0; r < 4; ++r) {
                const int row = row0 + r;
                const float v = acc[i][j][r] + bv;
                if (C)
                    C[(size_t)row * N + col] = (bf16_t)v;
                if (Cacc) {
                    const size_t idx = (size_t)row * N + col;
                    Cacc[idx] = accFirst ? v : (Cacc[idx] + v);
                }
                if (qk) {
                    const int hh  = col / 1536;
                    const int off = col - hh * 1536;
                    const int bb  = row >> 11;
                    const int ss  = row & 2047;
                    if (off < 1024)
                        qk[((size_t)((bb * hmul + hh) * 2048 + ss)) * 1024 + off] = (bf16_t)v;
                    else
                        vT[((size_t)((bb * hmul + hh) * 512 + (off - 1024))) * 2048 + ss] = (bf16_t)v;
                }
            }
        }
    }
}

// ---------------------------------------------------------------------------
// GEMM 256x256, same schedule as gemm_db (gload_lds dbuf, counted drain).
// 512 thr / 8 waves (2m x 4n), per-wave 128x64 output (acc[8][4]).
// LDS 128 KB -> 1 block/CU, 2 waves/SIMD (VGPR cap 256, est ~230).
// Grid n-major: gridDim.x = M/256, gridDim.y = N/256; XCD chunk = contiguous
// sbid range -> 6 W-panels (4.6 MB) pinned per XCD L2, A streamed.
// ---------------------------------------------------------------------------
__global__ __launch_bounds__(512, 2)
void gemm_db256(const bf16_t* __restrict__ A, int lda,
                const bf16_t* __restrict__ W, int ldw,
                const float* __restrict__ bias,
                bf16_t* __restrict__ C, int N, int K,
                bf16_t* __restrict__ qk, bf16_t* __restrict__ vT, int hmul)
{
    __shared__ __align__(16) bf16_t Ls[2][2][256 * BK];   // [buf][A/W], 128 KB

    const int tid  = threadIdx.x;
    const int wave = tid >> 6;
    const int lane = tid & 63;
    const int quad = lane >> 4;
    const int l16  = lane & 15;

    // ---- bijective XCD swizzle over n-major bid ----
    const int nwg = gridDim.x * gridDim.y;
    int bid = blockIdx.y * gridDim.x + blockIdx.x;
    bid = (bid & 7) * (nwg >> 3) + (bid >> 3);
    const int bm = (bid % gridDim.x) * 256;   // m minor -> W-panel reuse per XCD
    const int bn = (bid / gridDim.x) * 256;

    const int wm = (wave >> 2) * 128;   // 0 or 128
    const int wn = (wave & 3) * 64;     // 0..192

    // ---- staging bases: slot = it*512+tid; row = slot>>3 (0..255) ----
    const bf16_t* asrc[4]; const bf16_t* wsrc[4]; int ldo[4];
    #pragma unroll
    for (int it = 0; it < 4; ++it) {
        const int slot = it * 512 + tid;
        const int row  = slot >> 3;
        const int gs   = (slot & 7) ^ (row & 7);
        asrc[it] = A + (size_t)(bm + row) * lda + gs * 8;
        wsrc[it] = W + (size_t)(bn + row) * ldw + gs * 8;
        ldo[it]  = slot * 8;
    }

    auto stage = [&](int bsel, int k0) {
        bf16_t* da = &Ls[bsel][0][0];
        bf16_t* dw = &Ls[bsel][1][0];
        #pragma unroll
        for (int it = 0; it < 4; ++it) {
            async_cp16(asrc[it] + k0, da + ldo[it]);
            async_cp16(wsrc[it] + k0, dw + ldo[it]);
        }
    };

    f32x4 acc[8][4] = {};
    const int m7 = l16 & 7;

    stage(0, 0);
    wait_vm0();
    __syncthreads();

    const int nsteps = K / BK;
    for (int t = 0; t < nsteps; ++t) {
        const int b = t & 1;
        if (t + 1 < nsteps) stage(b ^ 1, (t + 1) * BK);

        const bf16_t* Ab = &Ls[b][0][0];
        const bf16_t* Wb = &Ls[b][1][0];
        __builtin_amdgcn_s_setprio(1);
        #pragma unroll
        for (int kk = 0; kk < 2; ++kk) {
            bf16x8 wf[4];
            #pragma unroll
            for (int j = 0; j < 4; ++j)
                wf[j] = *(const bf16x8*)(Wb + (wn + j * 16 + l16) * BK
                                            + (((kk * 4 + quad) ^ m7) * 8));
            #pragma unroll
            for (int i = 0; i < 8; ++i) {
                const bf16x8 af = *(const bf16x8*)(Ab + (wm + i * 16 + l16) * BK
                                                      + (((kk * 4 + quad) ^ m7) * 8));
                #pragma unroll
                for (int j = 0; j < 4; ++j)
                    acc[i][j] = __builtin_amdgcn_mfma_f32_16x16x32_bf16(af, wf[j], acc[i][j], 0, 0, 0);
            }
        }
        __builtin_amdgcn_s_setprio(0);

        wait_vm0();
        bar_lgkm();
    }

    #pragma unroll
    for (int j = 0; j < 4; ++j) {
        const int col = bn + wn + j * 16 + l16;
        const float bv = bias ? bias[col] : 0.f;
        #pragma unroll
        for (int i = 0; i < 8; ++i) {
            const int row0 = bm + wm + i * 16 + quad * 4;
            #pragma unroll
            for (int r = 0; r < 4; ++r) {
                const int row = row0 + r;
                const float v = acc[i][j][r] + bv;
                if (C)
                    C[(size_t)row * N + col] = (bf16_t)v;
                if (qk) {
                    const int hh  = col / 1536;
                    const int off = col - hh * 1536;
                    const int bb  = row >> 11;
                    const int ss  = row & 2047;
                    if (off < 1024)
                        qk[((size_t)((bb * hmul + hh) * 2048 + ss)) * 1024 + off] = (bf16_t)v;
                    else
                        vT[((size_t)((bb * hmul + hh) * 512 + (off - 1024))) * 2048 + ss] = (bf16_t)v;
                }
            }
        }
    }
}

// ---------------------------------------------------------------------------
// Flash attention (R11 schedule + XCD pair-grouping).
// Grid nPairs*Q blocks x 512 thr; work index W = p*qtiles + qt (p-major) so
// each XCD's contiguous chunk covers few pairs -> K/V working set per XCD
// drops 64 MB -> 8 MB. Requires gridDim.x % 8 == 0 (256/32/16 all OK).
// ---------------------------------------------------------------------------
__global__ __launch_bounds__(512, 2)
void attn(const bf16_t* __restrict__ qk, const bf16_t* __restrict__ vT,
          bf16_t* __restrict__ aout, int nPairs, int nH,
          int out_stride, int coloff_per_head)
{
    __shared__ __align__(16) bf16_t Ks[2 * 32 * 512];   // 64 KB
    __shared__ __align__(16) bf16_t Vs[2 * 512 * 32];   // 64 KB
    __shared__ __align__(16) bf16_t Plds[128 * 32];     //  8 KB
    __shared__ float aLds[128];
    __shared__ float lLds[128];

    const int tid  = threadIdx.x;
    const int wave = tid >> 6;
    const int lane = tid & 63;
    const int quad = lane >> 4;
    const int l16  = lane & 15;
    const int qh   = wave >> 2;       // PV q-half  (0..1)
    const int dw   = wave & 3;        // PV d-block (0..3)

    // ---- XCD pair-grouping: contiguous work chunks per XCD ----
    const int nblk   = gridDim.x;
    const int qtiles = nblk / nPairs;
    int wrk = blockIdx.x;
    wrk = (wrk & 7) * (nblk >> 3) + (wrk >> 3);
    const int p  = wrk / qtiles;      // pair (b*nH + h)
    const int qt = wrk % qtiles;

    const bf16_t* qp = qk + ((size_t)(p * 2048 + qt * 128 + wave * 16)) * 1024;
    const bf16_t* kp = qk + ((size_t)(p * 2048)) * 1024 + 512;
    const bf16_t* vp = vT + (size_t)p * 512 * 2048;

    // ---- per-thread staging base addresses (hoisted) ----
    const bf16_t* ksrc4[4]; const bf16_t* vsrc4[4];
    int kdo4[4], vdo4[4];
    #pragma unroll
    for (int it = 0; it < 4; ++it) {
        const int slot = it * 512 + tid;
        {   // K: row = slot/64 (0..31); LDS[r][s] = G[r][s^(r&7)]
            const int row  = slot >> 6;
            const int gseg = (slot & 63) ^ (row & 7);
            ksrc4[it] = kp + (size_t)row * 1024 + gseg * 8;
            kdo4[it]  = slot * 8;
        }
        {   // V: row = slot/4 (0..511); LDS[r][s] = G[r][s^((r>>1)&3)]
            const int row  = slot >> 2;
            const int gseg = (slot & 3) ^ ((slot >> 3) & 3);
            vsrc4[it] = vp + (size_t)row * 2048 + gseg * 8;
            vdo4[it]  = slot * 8;
        }
    }

    auto stageK = [&](int bsel, int key0) {
        bf16_t* dst = Ks + bsel * (32 * 512);
        const size_t koff = (size_t)key0 * 1024;
        #pragma unroll
        for (int it = 0; it < 4; ++it)
            async_cp16(ksrc4[it] + koff, dst + kdo4[it]);
    };
    auto stageV = [&](int bsel, int key0) {
        bf16_t* dst = Vs + bsel * (512 * 32);
        #pragma unroll
        for (int it = 0; it < 4; ++it)
            async_cp16(vsrc4[it] + key0, dst + vdo4[it]);
    };

    // ---- stage tile 0, preload Q fragments (read exactly once) ----
    stageK(0, 0);
    stageV(0, 0);
    bf16x8 qreg[16];
    #pragma unroll
    for (int ks = 0; ks < 16; ++ks)
        qreg[ks] = *(const bf16x8*)(qp + (size_t)l16 * 1024 + ks * 32 + quad * 8);

    f32x4 o[4][8] = {};                   // O[ (qh*64 + rt*16) x (dw*128 + ct*16) ]
    float m_i[4], l_p[4];
    #pragma unroll
    for (int r = 0; r < 4; ++r) { m_i[r] = -10000.f; l_p[r] = 0.f; }

    const float scale = 0.0441941738241592f;  // 1/sqrt(512)
    const int   kx8   = l16 & 7;              // Ks read swizzle key
    const int   kx4   = (l16 >> 1) & 3;       // Vs/P read swizzle key

    __syncthreads();   // drains vmcnt(0): K(0), V(0) resident

    for (int kt = 0; kt < 64; ++kt) {
        const int b = kt & 1;
        const bf16_t* Kb = Ks + b * (32 * 512);
        const bf16_t* Vb = Vs + b * (512 * 32);

        // ---- prefetch tile t+1 into the other buffer (full-step window) ----
        const int nkey = ((kt + 1) & 63) * 32;   // wrap: last stage is dead data
        stageK(b ^ 1, nkey);
        stageV(b ^ 1, nkey);

        // ---- S = Q K^T : own 16 q-rows x 32 keys, K from swizzled LDS ----
        f32x4 s[2] = {};
        __builtin_amdgcn_s_setprio(1);
        #pragma unroll
        for (int ks = 0; ks < 16; ++ks) {
            #pragma unroll
            for (int j = 0; j < 2; ++j) {
                const bf16x8 kf = *(const bf16x8*)(Kb + (j * 16 + l16) * 512
                                                      + (((ks * 4 + quad) ^ kx8) * 8));
                s[j] = __builtin_amdgcn_mfma_f32_16x16x32_bf16(qreg[ks], kf, s[j], 0, 0, 0);
            }
        }
        __builtin_amdgcn_s_setprio(0);
        s[0] *= scale; s[1] *= scale;

        // ---- defer-max softmax: common path has NO cross-lane ops ----
        float own[4];
        #pragma unroll
        for (int r = 0; r < 4; ++r)
            own[r] = fmaxf(s[0][r], s[1][r]);
        const float g = fmaxf(fmaxf(own[0] - m_i[0], own[1] - m_i[1]),
                              fmaxf(own[2] - m_i[2], own[3] - m_i[3]));
        float alpha[4] = {1.f, 1.f, 1.f, 1.f};
        if (__any(g > 8.f)) {             // rare: step 0 + genuine max growth
            #pragma unroll
            for (int r = 0; r < 4; ++r) {
                float v = own[r];
                v = fmaxf(v, __shfl_xor(v, 1));
                v = fmaxf(v, __shfl_xor(v, 2));
                v = fmaxf(v, __shfl_xor(v, 4));
                v = fmaxf(v, __shfl_xor(v, 8));
                const float mn = fmaxf(m_i[r], v);
                alpha[r] = __expf(m_i[r] - mn);
                m_i[r] = mn;
                l_p[r] *= alpha[r];
            }
        }
        if (l16 == 0) {
            #pragma unroll
            for (int r = 0; r < 4; ++r)
                aLds[wave * 16 + quad * 4 + r] = alpha[r];
        }

        // ---- P = exp(S - m) -> swizzled LDS; l partial per lane ----
        #pragma unroll
        for (int j = 0; j < 2; ++j)
            #pragma unroll
            for (int r = 0; r < 4; ++r) {
                const float pe = __expf(s[j][r] - m_i[r]);   // bounded by e^8
                l_p[r] += pe;
                const int row = wave * 16 + quad * 4 + r;
                const int sg  = (j * 2 + (l16 >> 3)) ^ (((quad * 4 + r) >> 1) & 3);
                Plds[row * 32 + sg * 8 + (l16 & 7)] = (bf16_t)pe;
            }

        bar_lgkm();        // B1: P/alpha visible. NO vmcnt drain.

        // ---- rescale O by shared alphas (skipped when all 1 — common) ----
        #pragma unroll
        for (int rt = 0; rt < 4; ++rt) {
            const float a0 = aLds[qh * 64 + rt * 16 + quad * 4 + 0];
            const float a1 = aLds[qh * 64 + rt * 16 + quad * 4 + 1];
            const float a2 = aLds[qh * 64 + rt * 16 + quad * 4 + 2];
            const float a3 = aLds[qh * 64 + rt * 16 + quad * 4 + 3];
            if (a0 != 1.f || a1 != 1.f || a2 != 1.f || a3 != 1.f) {
                #pragma unroll
                for (int ct = 0; ct < 8; ++ct) {
                    f32x4 t = o[rt][ct];
                    t[0] *= a0; t[1] *= a1; t[2] *= a2; t[3] *= a3;
                    o[rt][ct] = t;
                }
            }
        }

        // ---- O += P V : wave tile [64q x 128d] ----
        __builtin_amdgcn_s_setprio(1);
        bf16x8 pa[4];
        #pragma unroll
        for (int rt = 0; rt < 4; ++rt)
            pa[rt] = *(const bf16x8*)(Plds + (qh * 64 + rt * 16 + l16) * 32
                                           + ((quad ^ kx4) * 8));
        #pragma unroll
        for (int ct = 0; ct < 8; ++ct) {
            const bf16x8 vf = *(const bf16x8*)(Vb + (dw * 128 + ct * 16 + l16) * 32
                                                  + ((quad ^ kx4) * 8));
            #pragma unroll
            for (int rt = 0; rt < 4; ++rt)
                o[rt][ct] = __builtin_amdgcn_mfma_f32_16x16x32_bf16(pa[rt], vf, o[rt][ct], 0, 0, 0);
        }
        __builtin_amdgcn_s_setprio(0);

        wait_vm0();        // tile t+1 fills landed (issued at step top)
        bar_lgkm();        // Bend: buffers b^1 ready; b free to restage
    }

    // ---- epilogue: reduce l partials once, share via LDS, write O ----
    #pragma unroll
    for (int r = 0; r < 4; ++r) {
        float t = l_p[r];
        t += __shfl_xor(t, 1);
        t += __shfl_xor(t, 2);
        t += __shfl_xor(t, 4);
        t += __shfl_xor(t, 8);
        if (l16 == 0) lLds[wave * 16 + quad * 4 + r] = t;
    }
    __syncthreads();

    const int b_out  = p / nH;
    const int coloff = (p % nH) * coloff_per_head + dw * 128;
    #pragma unroll
    for (int rt = 0; rt < 4; ++rt) {
        #pragma unroll
        for (int r = 0; r < 4; ++r) {
            const float linv = 1.f / lLds[qh * 64 + rt * 16 + quad * 4 + r];
            const int row = b_out * 2048 + qt * 128 + qh * 64 + rt * 16 + quad * 4 + r;
            #pragma unroll
            for (int ct = 0; ct < 8; ++ct)
                aout[(size_t)row * out_stride + coloff + ct * 16 + l16] =
                    (bf16_t)(o[rt][ct][r] * linv);
        }
    }
}

// ---------------------------------------------------------------------------
extern "C" void kernel_launch(void* const* d_in, const int* in_sizes, int n_in,
                              void* d_out, int out_size, void* d_ws, size_t ws_size,
                              hipStream_t stream)
{
    const float* x       = (const float*)d_in[0];  // [4096, 512]   f32
    const float* W_sep   = (const float*)d_in[1];  // [1536, 512]   f32
    const float* b_sep   = (const float*)d_in[2];  // [1536]        f32
    const float* W_multi = (const float*)d_in[3];  // [12288, 1536] f32
    const float* b_multi = (const float*)d_in[4];  // [12288]       f32
    const float* W_res   = (const float*)d_in[5];  // [512, 4096]   f32
    const float* b_res   = (const float*)d_in[6];  // [512]         f32
    float* out = (float*)d_out;                    // [4096, 512]   f32

    char* ws = (char*)d_ws;
    const dim3 blk(256);
    const dim3 ablk(512);

    if (ws_size >= 160956416ull) {
        // ------------- tier 1: 161 MB, whole-problem dispatches -------------
        bf16_t* wmb = (bf16_t*)(ws);                   // [12288,1536] 37.75 MB
        bf16_t* av  = (bf16_t*)(ws);                   // [4096,4096]  33.55 MB (over wmb, dead)
        bf16_t* xb  = (bf16_t*)(ws +  37748736ull);    // [4096,512]    4.19 MB
        bf16_t* wsb = (bf16_t*)(ws +  41943040ull);    // [1536,512]    1.57 MB
        bf16_t* wrb = (bf16_t*)(ws +  43515904ull);    // [512,4096]    4.19 MB
        bf16_t* h1  = (bf16_t*)(ws +  47710208ull);    // [4096,1536]  12.58 MB
        bf16_t* qk  = (bf16_t*)(ws +  60293120ull);    // [2,8,2048,1024] 67.11 MB
        bf16_t* vT  = (bf16_t*)(ws + 127401984ull);    // [2,8,512,2048]  33.55 MB

        f32_to_bf16<<<dim3( 2048), blk, 0, stream>>>(x,       xb,  2097152 / 4);
        f32_to_bf16<<<dim3(  768), blk, 0, stream>>>(W_sep,   wsb,  786432 / 4);
        f32_to_bf16<<<dim3(18432), blk, 0, stream>>>(W_multi, wmb, 18874368 / 4);
        f32_to_bf16<<<dim3( 2048), blk, 0, stream>>>(W_res,   wrb,  2097152 / 4);

        gemm_db<<<dim3(12, 32), blk, 0, stream>>>(xb, 512, wsb, 512, b_sep,
                                                  h1, nullptr, 0, 1536, 512,
                                                  nullptr, nullptr, 0);
        gemm_db256<<<dim3(16, 48), ablk, 0, stream>>>(h1, 1536, wmb, 1536, b_multi,
                                                      nullptr, 12288, 1536,
                                                      qk, vT, 8);
        attn<<<dim3(256), ablk, 0, stream>>>(qk, vT, av, 16, 8, 4096, 512);
        gemm_db<<<dim3(4, 32), blk, 0, stream>>>(av, 4096, wrb, 4096, b_res,
                                                 nullptr, out, 1, 512, 4096,
                                                 nullptr, nullptr, 0);
    } else if (ws_size >= 39845888ull) {
        // ------------- tier 2: 39.8 MB, per-head streaming -------------
        bf16_t* h1    = (bf16_t*)(ws);                 // [4096,1536]  12.58 MB
        bf16_t* xb    = (bf16_t*)(ws + 12582912ull);   // [4096,512]    4.19 MB (dead after GEMM1)
        bf16_t* av_h  = (bf16_t*)(ws + 12582912ull);   //   reuse: [4096,512] bf16
        bf16_t* wsb   = (bf16_t*)(ws + 16777216ull);   // [1536,512]    1.57 MB
        bf16_t* wrb   = (bf16_t*)(ws + 18350080ull);   // [512,4096]    4.19 MB
        bf16_t* wmb_h = (bf16_t*)(ws + 22544384ull);   // [1536,1536]   4.72 MB
        bf16_t* qk_h  = (bf16_t*)(ws + 27262976ull);   // [2,2048,1024] 8.39 MB
        bf16_t* vT_h  = (bf16_t*)(ws + 35651584ull);   // [2,512,2048]  4.19 MB

        f32_to_bf16<<<dim3(2048), blk, 0, stream>>>(x,     xb,  2097152 / 4);
        f32_to_bf16<<<dim3( 768), blk, 0, stream>>>(W_sep, wsb,  786432 / 4);
        f32_to_bf16<<<dim3(2048), blk, 0, stream>>>(W_res, wrb,  2097152 / 4);

        gemm_db<<<dim3(12, 32), blk, 0, stream>>>(xb, 512, wsb, 512, b_sep,
                                                  h1, nullptr, 0, 1536, 512,
                                                  nullptr, nullptr, 0);
        for (int h = 0; h < 8; ++h) {
            f32_to_bf16<<<dim3(2304), blk, 0, stream>>>(W_multi + (size_t)h * 1536 * 1536,
                                                        wmb_h, 2359296 / 4);
            gemm_db<<<dim3(12, 32), blk, 0, stream>>>(h1, 1536, wmb_h, 1536,
                    b_multi + h * 1536, nullptr, nullptr, 0, 1536, 1536,
                    qk_h, vT_h, 1);
            attn<<<dim3(32), ablk, 0, stream>>>(qk_h, vT_h, av_h, 2, 1, 512, 0);
            gemm_db<<<dim3(4, 32), blk, 0, stream>>>(av_h, 512, wrb + h * 512, 4096,
                    (h == 0) ? b_res : nullptr, nullptr, out, (h == 0) ? 1 : 0,
                    512, 512, nullptr, nullptr, 0);
        }
    } else {
        // ------------- tier 3: exactly 32 MiB, per-(batch,head) -------------
        bf16_t* h1    = (bf16_t*)(ws);                 // [4096,1536]  12.58 MB
        bf16_t* xb    = (bf16_t*)(ws + 12582912ull);   // [4096,512]    4.19 MB (dead after GEMM1)
        bf16_t* av_bh = (bf16_t*)(ws + 12582912ull);   //   reuse: [2048,512] bf16
        bf16_t* wsb   = (bf16_t*)(ws + 16777216ull);   // [1536,512]    1.57 MB
        bf16_t* wrb   = (bf16_t*)(ws + 18350080ull);   // [512,4096]    4.19 MB
        bf16_t* wmb_h = (bf16_t*)(ws + 22544384ull);   // [1536,1536]   4.72 MB
        bf16_t* qk_bh = (bf16_t*)(ws + 27262976ull);   // [2048,1024]   4.19 MB
        bf16_t* vT_bh = (bf16_t*)(ws + 31457280ull);   // [512,2048]    2.10 MB

        f32_to_bf16<<<dim3(2048), blk, 0, stream>>>(x,     xb,  2097152 / 4);
        f32_to_bf16<<<dim3( 768), blk, 0, stream>>>(W_sep, wsb,  786432 / 4);
        f32_to_bf16<<<dim3(2048), blk, 0, stream>>>(W_res, wrb,  2097152 / 4);

        gemm_db<<<dim3(12, 32), blk, 0, stream>>>(xb, 512, wsb, 512, b_sep,
                                                  h1, nullptr, 0, 1536, 512,
                                                  nullptr, nullptr, 0);
        for (int h = 0; h < 8; ++h) {
            f32_to_bf16<<<dim3(2304), blk, 0, stream>>>(W_multi + (size_t)h * 1536 * 1536,
                                                        wmb_h, 2359296 / 4);
            for (int b = 0; b < 2; ++b) {
                gemm_db<<<dim3(12, 16), blk, 0, stream>>>(h1 + (size_t)b * 2048 * 1536, 1536,
                        wmb_h, 1536, b_multi + h * 1536,
                        nullptr, nullptr, 0, 1536, 1536, qk_bh, vT_bh, 1);
                attn<<<dim3(16), ablk, 0, stream>>>(qk_bh, vT_bh, av_bh, 1, 1, 512, 0);
                gemm_db<<<dim3(4, 16), blk, 0, stream>>>(av_bh, 512, wrb + h * 512, 4096,
                        (h == 0) ? b_res : nullptr, nullptr, out + (size_t)b * 2048 * 512,
                        (h == 0) ? 1 : 0, 512, 512, nullptr, nullptr, 0);
            }
        }
    }
}